// Round 2
// baseline (391.422 us; speedup 1.0000x reference)
//
#include <hip/hip_runtime.h>

// Tensor-ring layer v2: three register-tiled fp32 GEMMs, no LDS inner loops.
//   AT[pq][ij*64+ac]        = sum_b f0[i,a,b,p] f1[j,b,c,q]        (1 MB)
//   BT[(ac*64+st)][kl]      = sum_d f2[k,c,d,s] f3[l,d,a,t]        (1 MB)
//   CA[ij*64+ac][st*64+o]   = sum_pq AT[pq][.] core[pq][st*64+o]   (67 MB, ws)
//   T4[ij*64+kl][o]        += split-K atomics over (ac,st)
//   Y = x @ T4 (split-K atomics), out = Y @ OF + bias
// ws floats: AT 0, BT 262144, T4 524288, Y 786432, CA 1048576..17825792

#define WS_NEED ((size_t)17825792 * 4)

// ---------------- new path ----------------

__global__ __launch_bounds__(256) void k_fac(const float* __restrict__ f0,
                                             const float* __restrict__ f1,
                                             const float* __restrict__ f2,
                                             const float* __restrict__ f3,
                                             float* __restrict__ AT,
                                             float* __restrict__ BT,
                                             float* __restrict__ zdst) {
  int tid = threadIdx.x;
  int bb = blockIdx.x;
  if (bb >= 32) {                         // zero T4+Y (contiguous 524288 floats)
    int zb = bb - 32;                     // 128 blocks * 1024 float4
    float4* z4 = reinterpret_cast<float4*>(zdst);
#pragma unroll
    for (int r = 0; r < 4; ++r)
      z4[zb * 1024 + r * 256 + tid] = make_float4(0.f, 0.f, 0.f, 0.f);
    return;
  }
  __shared__ float u[4096], v[4096];
  const float* fu = (bb < 16) ? f0 : f2;
  const float* fv = (bb < 16) ? f1 : f3;
#pragma unroll
  for (int r = 0; r < 4; ++r) {
    reinterpret_cast<float4*>(u)[r * 256 + tid] = reinterpret_cast<const float4*>(fu)[r * 256 + tid];
    reinterpret_cast<float4*>(v)[r * 256 + tid] = reinterpret_cast<const float4*>(fv)[r * 256 + tid];
  }
  __syncthreads();
  if (bb < 16) {
    // AT[pq*4096 + (ij*64+ac)]
    for (int pqi = 0; pqi < 4; ++pqi) {
      int pq = bb * 4 + pqi, p = pq >> 3, q = pq & 7;
      for (int it = 0; it < 16; ++it) {
        int n = it * 256 + tid;           // ij*64+ac
        int i = n >> 9, j = (n >> 6) & 7, a = (n >> 3) & 7, c = n & 7;
        float acc = 0.f;
#pragma unroll
        for (int b = 0; b < 8; ++b)
          acc = fmaf(u[i * 512 + a * 64 + b * 8 + p], v[j * 512 + b * 64 + c * 8 + q], acc);
        AT[pq * 4096 + n] = acc;
      }
    }
  } else {
    int b2 = bb - 16;
    // BT[(ac*64+st)*64 + kl]
    for (int it = 0; it < 64; ++it) {
      int lk = it * 4 + (tid >> 6);
      int kl = tid & 63;
      int Kr = b2 * 256 + lk;
      int ac = Kr >> 6, st = Kr & 63;
      int a = ac >> 3, c = ac & 7, s = st >> 3, t = st & 7;
      int k = kl >> 3, l = kl & 7;
      float acc = 0.f;
#pragma unroll
      for (int d = 0; d < 8; ++d)
        acc = fmaf(u[k * 512 + c * 64 + d * 8 + s], v[l * 512 + d * 8 * 8 + a * 8 + t], acc);
      BT[Kr * 64 + kl] = acc;
    }
  }
}

// CA = AT^T(4096x64) @ core2(64x4096); tile 128x128, 8x8 per thread, K=64
__global__ __launch_bounds__(256) void k_ca(const float* __restrict__ AT,
                                            const float* __restrict__ core,
                                            float* __restrict__ CA) {
  int mt = blockIdx.x >> 5, nt = blockIdx.x & 31;
  int tr = threadIdx.x >> 4, tc = threadIdx.x & 15;
  int m0 = mt * 128 + tr * 8, n0 = nt * 128 + tc * 8;
  const float4* Ap = reinterpret_cast<const float4*>(AT + m0);    // row k: +k*1024
  const float4* Cp = reinterpret_cast<const float4*>(core + n0);
  float acc[8][8];
#pragma unroll
  for (int r = 0; r < 8; ++r)
#pragma unroll
    for (int c = 0; c < 8; ++c) acc[r][c] = 0.f;

  float4 a0 = Ap[0], a1 = Ap[1], b0 = Cp[0], b1 = Cp[1];
  for (int k = 0; k < 64; ++k) {
    int kn = (k < 63) ? k + 1 : 63;       // clamped prefetch (no OOB)
    float4 na0 = Ap[kn * 1024], na1 = Ap[kn * 1024 + 1];
    float4 nb0 = Cp[kn * 1024], nb1 = Cp[kn * 1024 + 1];
    float au[8] = {a0.x, a0.y, a0.z, a0.w, a1.x, a1.y, a1.z, a1.w};
    float bu[8] = {b0.x, b0.y, b0.z, b0.w, b1.x, b1.y, b1.z, b1.w};
#pragma unroll
    for (int r = 0; r < 8; ++r)
#pragma unroll
      for (int c = 0; c < 8; ++c)
        acc[r][c] = fmaf(au[r], bu[c], acc[r][c]);
    a0 = na0; a1 = na1; b0 = nb0; b1 = nb1;
  }
#pragma unroll
  for (int r = 0; r < 8; ++r) {
    float4* dst = reinterpret_cast<float4*>(CA + (size_t)(m0 + r) * 4096 + n0);
    dst[0] = make_float4(acc[r][0], acc[r][1], acc[r][2], acc[r][3]);
    dst[1] = make_float4(acc[r][4], acc[r][5], acc[r][6], acc[r][7]);
  }
}

#define FMA16(BV, CV)                                            \
  {                                                              \
    float bu_[4] = {BV.x, BV.y, BV.z, BV.w};                     \
    float cu_[4] = {CV.x, CV.y, CV.z, CV.w};                     \
    _Pragma("unroll") for (int r_ = 0; r_ < 4; ++r_)             \
        _Pragma("unroll") for (int c_ = 0; c_ < 4; ++c_)         \
            acc[r_][c_] = fmaf(bu_[r_], cu_[c_], acc[r_][c_]);   \
  }

// T4_ij = BT-chunk^T @ CA_ij-chunk, split-K x16 via atomics
__global__ __launch_bounds__(256) void k_step2(const float* __restrict__ BT,
                                               const float* __restrict__ CA,
                                               float* __restrict__ T4) {
  int ij = blockIdx.x >> 4, kc = blockIdx.x & 15;
  int tr = threadIdx.x >> 4, tc = threadIdx.x & 15;
  int kl0 = tr * 4, o0 = tc * 4;
  const float4* Bp = reinterpret_cast<const float4*>(BT + (size_t)kc * 16384 + kl0);
  const float4* Cp = reinterpret_cast<const float4*>(CA + (size_t)ij * 262144 + (size_t)kc * 16384 + o0);
  float acc[4][4] = {{0.f}};
  float4 b0 = Bp[0], c0 = Cp[0];
  float4 b1 = Bp[16], c1 = Cp[16];
  for (int k = 0; k < 256; k += 2) {
    int k2 = (k + 2 < 256) ? k + 2 : 254;
    int k3 = (k + 3 < 256) ? k + 3 : 255;
    float4 nb0 = Bp[k2 * 16], nc0 = Cp[k2 * 16];
    FMA16(b0, c0);
    float4 nb1 = Bp[k3 * 16], nc1 = Cp[k3 * 16];
    FMA16(b1, c1);
    b0 = nb0; c0 = nc0; b1 = nb1; c1 = nc1;
  }
#pragma unroll
  for (int r = 0; r < 4; ++r)
#pragma unroll
    for (int c = 0; c < 4; ++c)
      atomicAdd(&T4[(size_t)(ij * 64 + kl0 + r) * 64 + o0 + c], acc[r][c]);
}

// Y = x @ T4, split-K x16 via atomics, 2-deep prefetch on streamed x
__global__ __launch_bounds__(256) void k_y2(const float* __restrict__ x,
                                            const float* __restrict__ T4,
                                            float* __restrict__ Y) {
  int mt = blockIdx.x >> 4, kc = blockIdx.x & 15;
  int tr = threadIdx.x >> 4, tc = threadIdx.x & 15;
  int r0 = mt * 64 + tr * 4, o0 = tc * 4;
  int kb = kc * 256;
  const float4* xp0 = reinterpret_cast<const float4*>(x + (size_t)(r0 + 0) * 4096 + kb);
  const float4* xp1 = reinterpret_cast<const float4*>(x + (size_t)(r0 + 1) * 4096 + kb);
  const float4* xp2 = reinterpret_cast<const float4*>(x + (size_t)(r0 + 2) * 4096 + kb);
  const float4* xp3 = reinterpret_cast<const float4*>(x + (size_t)(r0 + 3) * 4096 + kb);
  const float4* tp = reinterpret_cast<const float4*>(T4 + (size_t)kb * 64 + o0);
  float acc[4][4] = {{0.f}};

  float4 xa0 = xp0[0], xa1 = xp1[0], xa2 = xp2[0], xa3 = xp3[0];
  float4 ta0 = tp[0], ta1 = tp[16], ta2 = tp[32], ta3 = tp[48];
  float4 xb0 = xp0[1], xb1 = xp1[1], xb2 = xp2[1], xb3 = xp3[1];
  float4 tb0 = tp[64], tb1 = tp[80], tb2 = tp[96], tb3 = tp[112];

#define YSTEP(X0, X1, X2, X3, T0, T1, T2, T3)                                      \
  {                                                                                \
    float t00 = T0.x, t01 = T0.y, t02 = T0.z, t03 = T0.w;                          \
    float t10 = T1.x, t11 = T1.y, t12 = T1.z, t13 = T1.w;                          \
    float t20 = T2.x, t21 = T2.y, t22 = T2.z, t23 = T2.w;                          \
    float t30 = T3.x, t31 = T3.y, t32 = T3.z, t33 = T3.w;                          \
    acc[0][0] = fmaf(X0.x, t00, fmaf(X0.y, t10, fmaf(X0.z, t20, fmaf(X0.w, t30, acc[0][0])))); \
    acc[0][1] = fmaf(X0.x, t01, fmaf(X0.y, t11, fmaf(X0.z, t21, fmaf(X0.w, t31, acc[0][1])))); \
    acc[0][2] = fmaf(X0.x, t02, fmaf(X0.y, t12, fmaf(X0.z, t22, fmaf(X0.w, t32, acc[0][2])))); \
    acc[0][3] = fmaf(X0.x, t03, fmaf(X0.y, t13, fmaf(X0.z, t23, fmaf(X0.w, t33, acc[0][3])))); \
    acc[1][0] = fmaf(X1.x, t00, fmaf(X1.y, t10, fmaf(X1.z, t20, fmaf(X1.w, t30, acc[1][0])))); \
    acc[1][1] = fmaf(X1.x, t01, fmaf(X1.y, t11, fmaf(X1.z, t21, fmaf(X1.w, t31, acc[1][1])))); \
    acc[1][2] = fmaf(X1.x, t02, fmaf(X1.y, t12, fmaf(X1.z, t22, fmaf(X1.w, t32, acc[1][2])))); \
    acc[1][3] = fmaf(X1.x, t03, fmaf(X1.y, t13, fmaf(X1.z, t23, fmaf(X1.w, t33, acc[1][3])))); \
    acc[2][0] = fmaf(X2.x, t00, fmaf(X2.y, t10, fmaf(X2.z, t20, fmaf(X2.w, t30, acc[2][0])))); \
    acc[2][1] = fmaf(X2.x, t01, fmaf(X2.y, t11, fmaf(X2.z, t21, fmaf(X2.w, t31, acc[2][1])))); \
    acc[2][2] = fmaf(X2.x, t02, fmaf(X2.y, t12, fmaf(X2.z, t22, fmaf(X2.w, t32, acc[2][2])))); \
    acc[2][3] = fmaf(X2.x, t03, fmaf(X2.y, t13, fmaf(X2.z, t23, fmaf(X2.w, t33, acc[2][3])))); \
    acc[3][0] = fmaf(X3.x, t00, fmaf(X3.y, t10, fmaf(X3.z, t20, fmaf(X3.w, t30, acc[3][0])))); \
    acc[3][1] = fmaf(X3.x, t01, fmaf(X3.y, t11, fmaf(X3.z, t21, fmaf(X3.w, t31, acc[3][1])))); \
    acc[3][2] = fmaf(X3.x, t02, fmaf(X3.y, t12, fmaf(X3.z, t22, fmaf(X3.w, t32, acc[3][2])))); \
    acc[3][3] = fmaf(X3.x, t03, fmaf(X3.y, t13, fmaf(X3.z, t23, fmaf(X3.w, t33, acc[3][3])))); \
  }

  for (int s = 0; s < 64; s += 2) {
    int s2 = (s + 2 < 64) ? s + 2 : 62;
    int s3 = (s + 3 < 64) ? s + 3 : 63;
    float4 nx0 = xp0[s2], nx1 = xp1[s2], nx2 = xp2[s2], nx3 = xp3[s2];
    float4 nt0 = tp[s2 * 64], nt1 = tp[s2 * 64 + 16], nt2 = tp[s2 * 64 + 32], nt3 = tp[s2 * 64 + 48];
    YSTEP(xa0, xa1, xa2, xa3, ta0, ta1, ta2, ta3);
    float4 mx0 = xp0[s3], mx1 = xp1[s3], mx2 = xp2[s3], mx3 = xp3[s3];
    float4 mt0 = tp[s3 * 64], mt1 = tp[s3 * 64 + 16], mt2 = tp[s3 * 64 + 32], mt3 = tp[s3 * 64 + 48];
    YSTEP(xb0, xb1, xb2, xb3, tb0, tb1, tb2, tb3);
    xa0 = nx0; xa1 = nx1; xa2 = nx2; xa3 = nx3;
    ta0 = nt0; ta1 = nt1; ta2 = nt2; ta3 = nt3;
    xb0 = mx0; xb1 = mx1; xb2 = mx2; xb3 = mx3;
    tb0 = mt0; tb1 = mt1; tb2 = mt2; tb3 = mt3;
  }
#pragma unroll
  for (int r = 0; r < 4; ++r)
#pragma unroll
    for (int c = 0; c < 4; ++c)
      atomicAdd(&Y[(size_t)(r0 + r) * 64 + o0 + c], acc[r][c]);
}

// out[b][f] = sum_o Y[b][o]*OF[o][f] + bias[f]
__global__ __launch_bounds__(256) void k_out(const float* __restrict__ Y,
                                             const float* __restrict__ OF_,
                                             const float* __restrict__ bias,
                                             float* __restrict__ out) {
  int b0 = blockIdx.x * 16;
  int tid = threadIdx.x;
  __shared__ float lY[1024];
  reinterpret_cast<float4*>(lY)[tid] =
      *reinterpret_cast<const float4*>(Y + (b0 + (tid >> 4)) * 64 + (tid & 15) * 4);
  __syncthreads();
  float4 acc[16];
#pragma unroll
  for (int r = 0; r < 16; ++r) acc[r] = make_float4(0.f, 0.f, 0.f, 0.f);
  for (int oo = 0; oo < 64; ++oo) {
    float4 w = *reinterpret_cast<const float4*>(OF_ + oo * 1024 + tid * 4);
#pragma unroll
    for (int r = 0; r < 16; ++r) {
      float yv = lY[r * 64 + oo];
      acc[r].x = fmaf(yv, w.x, acc[r].x);
      acc[r].y = fmaf(yv, w.y, acc[r].y);
      acc[r].z = fmaf(yv, w.z, acc[r].z);
      acc[r].w = fmaf(yv, w.w, acc[r].w);
    }
  }
  float4 bv = *reinterpret_cast<const float4*>(bias + tid * 4);
#pragma unroll
  for (int r = 0; r < 16; ++r) {
    float4 v = acc[r];
    v.x += bv.x; v.y += bv.y; v.z += bv.z; v.w += bv.w;
    *reinterpret_cast<float4*>(out + (b0 + r) * 1024 + tid * 4) = v;
  }
}

// ---------------- fallback path (round-1, verified) ----------------

__global__ __launch_bounds__(256) void k_g01(const float* __restrict__ f0,
                                             const float* __restrict__ f1,
                                             float* __restrict__ A) {
  int ij = blockIdx.x;
  int i = ij >> 3, j = ij & 7;
  __shared__ float lf0[512], lf1[512];
  int tid = threadIdx.x;
  if (tid < 128)
    reinterpret_cast<float4*>(lf0)[tid] = reinterpret_cast<const float4*>(f0 + i * 512)[tid];
  else
    reinterpret_cast<float4*>(lf1)[tid - 128] = reinterpret_cast<const float4*>(f1 + j * 512)[tid - 128];
  __syncthreads();
#pragma unroll
  for (int r = 0; r < 16; ++r) {
    int idx = r * 256 + tid;
    int ac = idx >> 6, pq = idx & 63;
    int a = ac >> 3, c = ac & 7, p = pq >> 3, q = pq & 7;
    float acc = 0.f;
#pragma unroll
    for (int b = 0; b < 8; ++b)
      acc = fmaf(lf0[a * 64 + b * 8 + p], lf1[b * 64 + c * 8 + q], acc);
    A[ij * 4096 + idx] = acc;
  }
}

__global__ __launch_bounds__(256) void k_g23(const float* __restrict__ f2,
                                             const float* __restrict__ f3,
                                             float* __restrict__ B) {
  int kl = blockIdx.x;
  int k = kl >> 3, l = kl & 7;
  __shared__ float lf2[512], lf3[512];
  int tid = threadIdx.x;
  if (tid < 128)
    reinterpret_cast<float4*>(lf2)[tid] = reinterpret_cast<const float4*>(f2 + k * 512)[tid];
  else
    reinterpret_cast<float4*>(lf3)[tid - 128] = reinterpret_cast<const float4*>(f3 + l * 512)[tid - 128];
  __syncthreads();
#pragma unroll
  for (int r = 0; r < 16; ++r) {
    int idx = r * 256 + tid;
    int ac = idx >> 6, st = idx & 63;
    int a = ac >> 3, c = ac & 7, s = st >> 3, t = st & 7;
    float acc = 0.f;
#pragma unroll
    for (int d = 0; d < 8; ++d)
      acc = fmaf(lf2[c * 64 + d * 8 + s], lf3[d * 64 + a * 8 + t], acc);
    B[kl * 4096 + idx] = acc;
  }
}

__global__ __launch_bounds__(256) void k_t4(const float* __restrict__ A,
                                            const float* __restrict__ B,
                                            const float* __restrict__ core,
                                            float* __restrict__ T4) {
  int bid = blockIdx.x;
  int ij = bid >> 4, kl0 = (bid & 15) * 4;
  __shared__ float lA[4096];
  __shared__ float lS[4][4096];
  int tid = threadIdx.x;
#pragma unroll
  for (int r = 0; r < 4; ++r)
    reinterpret_cast<float4*>(lA)[r * 256 + tid] =
        reinterpret_cast<const float4*>(A + ij * 4096)[r * 256 + tid];
  __syncthreads();
  int pq0 = (tid >> 4) << 2;
  int st04 = tid & 15;
#pragma unroll 1
  for (int m = 0; m < 4; ++m) {
    const float4* Bp = reinterpret_cast<const float4*>(B + (kl0 + m) * 4096);
    float acc[4][4] = {{0.f}};
    for (int ac = 0; ac < 64; ++ac) {
      float4 av = reinterpret_cast<float4*>(lA)[ac * 16 + (pq0 >> 2)];
      float4 bv = Bp[ac * 16 + st04];
      float au[4] = {av.x, av.y, av.z, av.w};
      float bu[4] = {bv.x, bv.y, bv.z, bv.w};
#pragma unroll
      for (int u = 0; u < 4; ++u)
#pragma unroll
        for (int v = 0; v < 4; ++v)
          acc[u][v] = fmaf(au[u], bu[v], acc[u][v]);
    }
    float4* S4 = reinterpret_cast<float4*>(lS[m]);
#pragma unroll
    for (int u = 0; u < 4; ++u)
      S4[(pq0 + u) * 16 + st04] = make_float4(acc[u][0], acc[u][1], acc[u][2], acc[u][3]);
  }
  __syncthreads();
  int o44 = tid & 15, seg = tid >> 4;
  const float4* c4 = reinterpret_cast<const float4*>(core);
  float4 r0 = {0, 0, 0, 0}, r1 = r0, r2 = r0, r3 = r0;
  for (int n = 0; n < 256; ++n) {
    int midx = seg * 256 + n;
    float4 cv = c4[midx * 16 + o44];
    float s0 = lS[0][midx], s1 = lS[1][midx], s2 = lS[2][midx], s3 = lS[3][midx];
    r0.x = fmaf(s0, cv.x, r0.x); r0.y = fmaf(s0, cv.y, r0.y);
    r0.z = fmaf(s0, cv.z, r0.z); r0.w = fmaf(s0, cv.w, r0.w);
    r1.x = fmaf(s1, cv.x, r1.x); r1.y = fmaf(s1, cv.y, r1.y);
    r1.z = fmaf(s1, cv.z, r1.z); r1.w = fmaf(s1, cv.w, r1.w);
    r2.x = fmaf(s2, cv.x, r2.x); r2.y = fmaf(s2, cv.y, r2.y);
    r2.z = fmaf(s2, cv.z, r2.z); r2.w = fmaf(s2, cv.w, r2.w);
    r3.x = fmaf(s3, cv.x, r3.x); r3.y = fmaf(s3, cv.y, r3.y);
    r3.z = fmaf(s3, cv.z, r3.z); r3.w = fmaf(s3, cv.w, r3.w);
  }
  float4* red = reinterpret_cast<float4*>(lA);
  red[(seg * 4 + 0) * 16 + o44] = r0;
  red[(seg * 4 + 1) * 16 + o44] = r1;
  red[(seg * 4 + 2) * 16 + o44] = r2;
  red[(seg * 4 + 3) * 16 + o44] = r3;
  __syncthreads();
  int m2 = tid >> 6, o = tid & 63;
  float t = 0.f;
#pragma unroll
  for (int s2 = 0; s2 < 16; ++s2) t += lA[(s2 * 4 + m2) * 64 + o];
  T4[(ij * 64 + kl0 + m2) * 64 + o] = t;
}

__global__ __launch_bounds__(256) void k_y(const float* __restrict__ x,
                                           const float* __restrict__ T4,
                                           float* __restrict__ Y) {
  int b0 = blockIdx.x * 16;
  __shared__ float lx[1024];
  int tid = threadIdx.x;
  int o = tid & 63, rg = tid >> 6;
  float acc0 = 0.f, acc1 = 0.f, acc2 = 0.f, acc3 = 0.f;
  const float4* lx4 = reinterpret_cast<const float4*>(lx);
  for (int kc = 0; kc < 4096; kc += 64) {
    __syncthreads();
    reinterpret_cast<float4*>(lx)[tid] =
        *reinterpret_cast<const float4*>(x + (b0 + (tid >> 4)) * 4096 + kc + (tid & 15) * 4);
    __syncthreads();
#pragma unroll 4
    for (int kk = 0; kk < 64; kk += 4) {
      float c0 = T4[(kc + kk + 0) * 64 + o];
      float c1 = T4[(kc + kk + 1) * 64 + o];
      float c2 = T4[(kc + kk + 2) * 64 + o];
      float c3 = T4[(kc + kk + 3) * 64 + o];
      float4 xv;
      xv = lx4[(rg * 4 + 0) * 16 + (kk >> 2)];
      acc0 = fmaf(xv.x, c0, fmaf(xv.y, c1, fmaf(xv.z, c2, fmaf(xv.w, c3, acc0))));
      xv = lx4[(rg * 4 + 1) * 16 + (kk >> 2)];
      acc1 = fmaf(xv.x, c0, fmaf(xv.y, c1, fmaf(xv.z, c2, fmaf(xv.w, c3, acc1))));
      xv = lx4[(rg * 4 + 2) * 16 + (kk >> 2)];
      acc2 = fmaf(xv.x, c0, fmaf(xv.y, c1, fmaf(xv.z, c2, fmaf(xv.w, c3, acc2))));
      xv = lx4[(rg * 4 + 3) * 16 + (kk >> 2)];
      acc3 = fmaf(xv.x, c0, fmaf(xv.y, c1, fmaf(xv.z, c2, fmaf(xv.w, c3, acc3))));
    }
  }
  Y[(b0 + rg * 4 + 0) * 64 + o] = acc0;
  Y[(b0 + rg * 4 + 1) * 64 + o] = acc1;
  Y[(b0 + rg * 4 + 2) * 64 + o] = acc2;
  Y[(b0 + rg * 4 + 3) * 64 + o] = acc3;
}

// ---------------- host ----------------

extern "C" void kernel_launch(void* const* d_in, const int* in_sizes, int n_in,
                              void* d_out, int out_size, void* d_ws, size_t ws_size,
                              hipStream_t stream) {
  const float* x    = (const float*)d_in[0];
  const float* f0   = (const float*)d_in[1];
  const float* f1   = (const float*)d_in[2];
  const float* f2   = (const float*)d_in[3];
  const float* f3   = (const float*)d_in[4];
  const float* core = (const float*)d_in[5];
  const float* ofac = (const float*)d_in[6];
  const float* bias = (const float*)d_in[7];
  float* out = (float*)d_out;
  float* ws = (float*)d_ws;

  if (ws_size >= WS_NEED) {
    float* AT = ws;
    float* BT = ws + 262144;
    float* T4 = ws + 524288;
    float* Yb = ws + 786432;
    float* CA = ws + 1048576;
    k_fac<<<160, 256, 0, stream>>>(f0, f1, f2, f3, AT, BT, T4);
    k_ca<<<1024, 256, 0, stream>>>(AT, core, CA);
    k_step2<<<1024, 256, 0, stream>>>(BT, CA, T4);
    k_y2<<<1024, 256, 0, stream>>>(x, T4, Yb);
    k_out<<<256, 256, 0, stream>>>(Yb, ofac, bias, out);
  } else {
    float* A  = ws;
    float* B  = A + 262144;
    float* T4 = B + 262144;
    float* Yb = T4 + 262144;
    k_g01<<<64, 256, 0, stream>>>(f0, f1, A);
    k_g23<<<64, 256, 0, stream>>>(f2, f3, B);
    k_t4<<<1024, 256, 0, stream>>>(A, B, core, T4);
    k_y<<<256, 256, 0, stream>>>(x, T4, Yb);
    k_out<<<256, 256, 0, stream>>>(Yb, ofac, bias, out);
  }
}

// Round 3
// 229.925 us; speedup vs baseline: 1.7024x; 1.7024x over previous
//
#include <hip/hip_runtime.h>

// Tensor-ring layer v3.
//   Build (round-1, verified, no atomics):
//     A  = g01[ij][ac][pq], B = g23[kl][ac][st]  (1 MB each)
//     T4[ijkl][o] via per-(ij,4kl) LDS contraction with core
//   New x-GEMM:
//     k_pack: T4 -> Bpack, bf16 hi/lo planes in MFMA B-fragment order (1 MB)
//     k_ymm : Y = x @ T4 via mfma_f32_16x16x32_bf16, bf16-split (3 products),
//             split-K x16 into separate partial buffers (NO atomics)
//     k_out2: reduce 16 partials + Y @ out_factor + bias
// ws floats: A 0, B 262144, T4 524288, Bpack 786432 (1MB as u16), Ypart 1048576..5242880

#define WS_NEED ((size_t)5242880 * 4)

typedef __attribute__((ext_vector_type(8))) short short8v;
typedef __attribute__((ext_vector_type(4))) float f32x4;

__device__ inline unsigned short f2bf(float f) {
  unsigned u = __builtin_bit_cast(unsigned, f);
  u += 0x7FFFu + ((u >> 16) & 1u);          // round-to-nearest-even
  return (unsigned short)(u >> 16);
}
__device__ inline float bf2f(unsigned short h) {
  return __builtin_bit_cast(float, (unsigned)h << 16);
}

// ---------------- T4 build (verified round-1) ----------------

__global__ __launch_bounds__(256) void k_g01(const float* __restrict__ f0,
                                             const float* __restrict__ f1,
                                             float* __restrict__ A) {
  int ij = blockIdx.x;
  int i = ij >> 3, j = ij & 7;
  __shared__ float lf0[512], lf1[512];
  int tid = threadIdx.x;
  if (tid < 128)
    reinterpret_cast<float4*>(lf0)[tid] = reinterpret_cast<const float4*>(f0 + i * 512)[tid];
  else
    reinterpret_cast<float4*>(lf1)[tid - 128] = reinterpret_cast<const float4*>(f1 + j * 512)[tid - 128];
  __syncthreads();
#pragma unroll
  for (int r = 0; r < 16; ++r) {
    int idx = r * 256 + tid;
    int ac = idx >> 6, pq = idx & 63;
    int a = ac >> 3, c = ac & 7, p = pq >> 3, q = pq & 7;
    float acc = 0.f;
#pragma unroll
    for (int b = 0; b < 8; ++b)
      acc = fmaf(lf0[a * 64 + b * 8 + p], lf1[b * 64 + c * 8 + q], acc);
    A[ij * 4096 + idx] = acc;
  }
}

__global__ __launch_bounds__(256) void k_g23(const float* __restrict__ f2,
                                             const float* __restrict__ f3,
                                             float* __restrict__ B) {
  int kl = blockIdx.x;
  int k = kl >> 3, l = kl & 7;
  __shared__ float lf2[512], lf3[512];
  int tid = threadIdx.x;
  if (tid < 128)
    reinterpret_cast<float4*>(lf2)[tid] = reinterpret_cast<const float4*>(f2 + k * 512)[tid];
  else
    reinterpret_cast<float4*>(lf3)[tid - 128] = reinterpret_cast<const float4*>(f3 + l * 512)[tid - 128];
  __syncthreads();
#pragma unroll
  for (int r = 0; r < 16; ++r) {
    int idx = r * 256 + tid;
    int ac = idx >> 6, st = idx & 63;
    int a = ac >> 3, c = ac & 7, s = st >> 3, t = st & 7;
    float acc = 0.f;
#pragma unroll
    for (int d = 0; d < 8; ++d)
      acc = fmaf(lf2[c * 64 + d * 8 + s], lf3[d * 64 + a * 8 + t], acc);
    B[kl * 4096 + idx] = acc;
  }
}

__global__ __launch_bounds__(256) void k_t4(const float* __restrict__ A,
                                            const float* __restrict__ B,
                                            const float* __restrict__ core,
                                            float* __restrict__ T4) {
  int bid = blockIdx.x;
  int ij = bid >> 4, kl0 = (bid & 15) * 4;
  __shared__ float lA[4096];
  __shared__ float lS[4][4096];
  int tid = threadIdx.x;
#pragma unroll
  for (int r = 0; r < 4; ++r)
    reinterpret_cast<float4*>(lA)[r * 256 + tid] =
        reinterpret_cast<const float4*>(A + ij * 4096)[r * 256 + tid];
  __syncthreads();
  int pq0 = (tid >> 4) << 2;
  int st04 = tid & 15;
#pragma unroll 1
  for (int m = 0; m < 4; ++m) {
    const float4* Bp = reinterpret_cast<const float4*>(B + (kl0 + m) * 4096);
    float acc[4][4] = {{0.f}};
    for (int ac = 0; ac < 64; ++ac) {
      float4 av = reinterpret_cast<float4*>(lA)[ac * 16 + (pq0 >> 2)];
      float4 bv = Bp[ac * 16 + st04];
      float au[4] = {av.x, av.y, av.z, av.w};
      float bu[4] = {bv.x, bv.y, bv.z, bv.w};
#pragma unroll
      for (int u = 0; u < 4; ++u)
#pragma unroll
        for (int v = 0; v < 4; ++v)
          acc[u][v] = fmaf(au[u], bu[v], acc[u][v]);
    }
    float4* S4 = reinterpret_cast<float4*>(lS[m]);
#pragma unroll
    for (int u = 0; u < 4; ++u)
      S4[(pq0 + u) * 16 + st04] = make_float4(acc[u][0], acc[u][1], acc[u][2], acc[u][3]);
  }
  __syncthreads();
  int o44 = tid & 15, seg = tid >> 4;
  const float4* c4 = reinterpret_cast<const float4*>(core);
  float4 r0 = {0, 0, 0, 0}, r1 = r0, r2 = r0, r3 = r0;
  for (int n = 0; n < 256; ++n) {
    int midx = seg * 256 + n;
    float4 cv = c4[midx * 16 + o44];
    float s0 = lS[0][midx], s1 = lS[1][midx], s2 = lS[2][midx], s3 = lS[3][midx];
    r0.x = fmaf(s0, cv.x, r0.x); r0.y = fmaf(s0, cv.y, r0.y);
    r0.z = fmaf(s0, cv.z, r0.z); r0.w = fmaf(s0, cv.w, r0.w);
    r1.x = fmaf(s1, cv.x, r1.x); r1.y = fmaf(s1, cv.y, r1.y);
    r1.z = fmaf(s1, cv.z, r1.z); r1.w = fmaf(s1, cv.w, r1.w);
    r2.x = fmaf(s2, cv.x, r2.x); r2.y = fmaf(s2, cv.y, r2.y);
    r2.z = fmaf(s2, cv.z, r2.z); r2.w = fmaf(s2, cv.w, r2.w);
    r3.x = fmaf(s3, cv.x, r3.x); r3.y = fmaf(s3, cv.y, r3.y);
    r3.z = fmaf(s3, cv.z, r3.z); r3.w = fmaf(s3, cv.w, r3.w);
  }
  float4* red = reinterpret_cast<float4*>(lA);
  red[(seg * 4 + 0) * 16 + o44] = r0;
  red[(seg * 4 + 1) * 16 + o44] = r1;
  red[(seg * 4 + 2) * 16 + o44] = r2;
  red[(seg * 4 + 3) * 16 + o44] = r3;
  __syncthreads();
  int m2 = tid >> 6, o = tid & 63;
  float t = 0.f;
#pragma unroll
  for (int s2 = 0; s2 < 16; ++s2) t += lA[(s2 * 4 + m2) * 64 + o];
  T4[(ij * 64 + kl0 + m2) * 64 + o] = t;
}

// ---------------- pack T4 into MFMA B-fragment order, bf16 hi/lo ----------------
// Bpack[kblk][nf][h][lane][j] : lane holds T4[k0 + 8*(lane>>4)+j][nf*16 + (lane&15)]

__global__ __launch_bounds__(256) void k_pack(const float* __restrict__ T4,
                                              unsigned short* __restrict__ Bp) {
  __shared__ float lT[2048];                // 32 k-rows x 64 cols
  int kb = blockIdx.x, t = threadIdx.x;     // 128 blocks
  reinterpret_cast<float4*>(lT)[t] = reinterpret_cast<const float4*>(T4 + kb * 2048)[t];
  reinterpret_cast<float4*>(lT)[t + 256] = reinterpret_cast<const float4*>(T4 + kb * 2048)[t + 256];
  __syncthreads();
#pragma unroll
  for (int it = 0; it < 2; ++it) {
    int item = it * 256 + t;                // (nf*2+h)*64 + lane
    int nf = item >> 7, h = (item >> 6) & 1, lane = item & 63;
    int kgg = lane >> 4, nn = nf * 16 + (lane & 15);
    short8v o;
#pragma unroll
    for (int j = 0; j < 8; ++j) {
      float v = lT[(kgg * 8 + j) * 64 + nn];
      unsigned short hh = f2bf(v);
      o[j] = (short)(h ? f2bf(v - bf2f(hh)) : hh);
    }
    *reinterpret_cast<short8v*>(Bp + (size_t)kb * 4096 + (size_t)item * 8) = o;
  }
}

// ---------------- Y = x @ T4, MFMA bf16-split, split-K x16, no atomics ----------------

__global__ __launch_bounds__(256) void k_ymm(const float* __restrict__ x,
                                             const unsigned short* __restrict__ Bp,
                                             float* __restrict__ Ypart) {
  int mt = blockIdx.x >> 4, kc = blockIdx.x & 15;   // 64 x 16
  int w = threadIdx.x >> 6, l = threadIdx.x & 63;
  int kg = l >> 4, lm = l & 15;
  const float4* xp = reinterpret_cast<const float4*>(
      x + (size_t)(mt * 64 + w * 16 + lm) * 4096 + kc * 256 + kg * 8);
  f32x4 acc0 = {0.f, 0.f, 0.f, 0.f}, acc1 = acc0, acc2 = acc0, acc3 = acc0;
#pragma unroll 1
  for (int s = 0; s < 8; ++s) {             // K-step = 32
    float4 xa = xp[s * 8], xb = xp[s * 8 + 1];
    float xs[8] = {xa.x, xa.y, xa.z, xa.w, xb.x, xb.y, xb.z, xb.w};
    short8v ah, al;
#pragma unroll
    for (int j = 0; j < 8; ++j) {
      unsigned short h = f2bf(xs[j]);
      ah[j] = (short)h;
      al[j] = (short)f2bf(xs[j] - bf2f(h));
    }
    const short8v* bp = reinterpret_cast<const short8v*>(Bp + (size_t)(kc * 8 + s) * 4096) + l;
    short8v bh0 = bp[0],   bl0 = bp[64];
    short8v bh1 = bp[128], bl1 = bp[192];
    short8v bh2 = bp[256], bl2 = bp[320];
    short8v bh3 = bp[384], bl3 = bp[448];
    acc0 = __builtin_amdgcn_mfma_f32_16x16x32_bf16(ah, bh0, acc0, 0, 0, 0);
    acc1 = __builtin_amdgcn_mfma_f32_16x16x32_bf16(ah, bh1, acc1, 0, 0, 0);
    acc2 = __builtin_amdgcn_mfma_f32_16x16x32_bf16(ah, bh2, acc2, 0, 0, 0);
    acc3 = __builtin_amdgcn_mfma_f32_16x16x32_bf16(ah, bh3, acc3, 0, 0, 0);
    acc0 = __builtin_amdgcn_mfma_f32_16x16x32_bf16(al, bh0, acc0, 0, 0, 0);
    acc1 = __builtin_amdgcn_mfma_f32_16x16x32_bf16(al, bh1, acc1, 0, 0, 0);
    acc2 = __builtin_amdgcn_mfma_f32_16x16x32_bf16(al, bh2, acc2, 0, 0, 0);
    acc3 = __builtin_amdgcn_mfma_f32_16x16x32_bf16(al, bh3, acc3, 0, 0, 0);
    acc0 = __builtin_amdgcn_mfma_f32_16x16x32_bf16(ah, bl0, acc0, 0, 0, 0);
    acc1 = __builtin_amdgcn_mfma_f32_16x16x32_bf16(ah, bl1, acc1, 0, 0, 0);
    acc2 = __builtin_amdgcn_mfma_f32_16x16x32_bf16(ah, bl2, acc2, 0, 0, 0);
    acc3 = __builtin_amdgcn_mfma_f32_16x16x32_bf16(ah, bl3, acc3, 0, 0, 0);
  }
  // D layout: col = lane&15, row = 4*(lane>>4)+r  (m89-verified)
  float* yb = Ypart + (size_t)kc * 262144 + (size_t)(mt * 64 + w * 16) * 64;
#pragma unroll
  for (int r = 0; r < 4; ++r) {
    yb[(kg * 4 + r) * 64 + 0  + lm] = acc0[r];
    yb[(kg * 4 + r) * 64 + 16 + lm] = acc1[r];
    yb[(kg * 4 + r) * 64 + 32 + lm] = acc2[r];
    yb[(kg * 4 + r) * 64 + 48 + lm] = acc3[r];
  }
}

// ---------------- reduce partials + Y @ OF + bias ----------------

__global__ __launch_bounds__(256) void k_out2(const float* __restrict__ Ypart,
                                              const float* __restrict__ OF_,
                                              const float* __restrict__ bias,
                                              float* __restrict__ out) {
  int b0 = blockIdx.x * 16;
  int tid = threadIdx.x;
  __shared__ float lY[1024];
  {
    size_t off = (size_t)(b0 + (tid >> 4)) * 64 + (tid & 15) * 4;
    float4 a = make_float4(0.f, 0.f, 0.f, 0.f);
#pragma unroll
    for (int kc = 0; kc < 16; ++kc) {
      float4 v = *reinterpret_cast<const float4*>(Ypart + (size_t)kc * 262144 + off);
      a.x += v.x; a.y += v.y; a.z += v.z; a.w += v.w;
    }
    *reinterpret_cast<float4*>(lY + tid * 4) = a;
  }
  __syncthreads();
  float4 acc[16];
#pragma unroll
  for (int r = 0; r < 16; ++r) acc[r] = make_float4(0.f, 0.f, 0.f, 0.f);
  for (int oo = 0; oo < 64; ++oo) {
    float4 w = *reinterpret_cast<const float4*>(OF_ + oo * 1024 + tid * 4);
#pragma unroll
    for (int r = 0; r < 16; ++r) {
      float yv = lY[r * 64 + oo];
      acc[r].x = fmaf(yv, w.x, acc[r].x);
      acc[r].y = fmaf(yv, w.y, acc[r].y);
      acc[r].z = fmaf(yv, w.z, acc[r].z);
      acc[r].w = fmaf(yv, w.w, acc[r].w);
    }
  }
  float4 bv = *reinterpret_cast<const float4*>(bias + tid * 4);
#pragma unroll
  for (int r = 0; r < 16; ++r) {
    float4 v = acc[r];
    v.x += bv.x; v.y += bv.y; v.z += bv.z; v.w += bv.w;
    *reinterpret_cast<float4*>(out + (b0 + r) * 1024 + tid * 4) = v;
  }
}

// ---------------- fallback (round-1 k_y/k_out, tiny ws) ----------------

__global__ __launch_bounds__(256) void k_y(const float* __restrict__ x,
                                           const float* __restrict__ T4,
                                           float* __restrict__ Y) {
  int b0 = blockIdx.x * 16;
  __shared__ float lx[1024];
  int tid = threadIdx.x;
  int o = tid & 63, rg = tid >> 6;
  float acc0 = 0.f, acc1 = 0.f, acc2 = 0.f, acc3 = 0.f;
  const float4* lx4 = reinterpret_cast<const float4*>(lx);
  for (int kc = 0; kc < 4096; kc += 64) {
    __syncthreads();
    reinterpret_cast<float4*>(lx)[tid] =
        *reinterpret_cast<const float4*>(x + (b0 + (tid >> 4)) * 4096 + kc + (tid & 15) * 4);
    __syncthreads();
#pragma unroll 4
    for (int kk = 0; kk < 64; kk += 4) {
      float c0 = T4[(kc + kk + 0) * 64 + o];
      float c1 = T4[(kc + kk + 1) * 64 + o];
      float c2 = T4[(kc + kk + 2) * 64 + o];
      float c3 = T4[(kc + kk + 3) * 64 + o];
      float4 xv;
      xv = lx4[(rg * 4 + 0) * 16 + (kk >> 2)];
      acc0 = fmaf(xv.x, c0, fmaf(xv.y, c1, fmaf(xv.z, c2, fmaf(xv.w, c3, acc0))));
      xv = lx4[(rg * 4 + 1) * 16 + (kk >> 2)];
      acc1 = fmaf(xv.x, c0, fmaf(xv.y, c1, fmaf(xv.z, c2, fmaf(xv.w, c3, acc1))));
      xv = lx4[(rg * 4 + 2) * 16 + (kk >> 2)];
      acc2 = fmaf(xv.x, c0, fmaf(xv.y, c1, fmaf(xv.z, c2, fmaf(xv.w, c3, acc2))));
      xv = lx4[(rg * 4 + 3) * 16 + (kk >> 2)];
      acc3 = fmaf(xv.x, c0, fmaf(xv.y, c1, fmaf(xv.z, c2, fmaf(xv.w, c3, acc3))));
    }
  }
  Y[(b0 + rg * 4 + 0) * 64 + o] = acc0;
  Y[(b0 + rg * 4 + 1) * 64 + o] = acc1;
  Y[(b0 + rg * 4 + 2) * 64 + o] = acc2;
  Y[(b0 + rg * 4 + 3) * 64 + o] = acc3;
}

__global__ __launch_bounds__(256) void k_out(const float* __restrict__ Y,
                                             const float* __restrict__ OF_,
                                             const float* __restrict__ bias,
                                             float* __restrict__ out) {
  int b0 = blockIdx.x * 16;
  int tid = threadIdx.x;
  __shared__ float lY[1024];
  reinterpret_cast<float4*>(lY)[tid] =
      *reinterpret_cast<const float4*>(Y + (b0 + (tid >> 4)) * 64 + (tid & 15) * 4);
  __syncthreads();
  float4 acc[16];
#pragma unroll
  for (int r = 0; r < 16; ++r) acc[r] = make_float4(0.f, 0.f, 0.f, 0.f);
  for (int oo = 0; oo < 64; ++oo) {
    float4 w = *reinterpret_cast<const float4*>(OF_ + oo * 1024 + tid * 4);
#pragma unroll
    for (int r = 0; r < 16; ++r) {
      float yv = lY[r * 64 + oo];
      acc[r].x = fmaf(yv, w.x, acc[r].x);
      acc[r].y = fmaf(yv, w.y, acc[r].y);
      acc[r].z = fmaf(yv, w.z, acc[r].z);
      acc[r].w = fmaf(yv, w.w, acc[r].w);
    }
  }
  float4 bv = *reinterpret_cast<const float4*>(bias + tid * 4);
#pragma unroll
  for (int r = 0; r < 16; ++r) {
    float4 v = acc[r];
    v.x += bv.x; v.y += bv.y; v.z += bv.z; v.w += bv.w;
    *reinterpret_cast<float4*>(out + (b0 + r) * 1024 + tid * 4) = v;
  }
}

// ---------------- host ----------------

extern "C" void kernel_launch(void* const* d_in, const int* in_sizes, int n_in,
                              void* d_out, int out_size, void* d_ws, size_t ws_size,
                              hipStream_t stream) {
  const float* x    = (const float*)d_in[0];
  const float* f0   = (const float*)d_in[1];
  const float* f1   = (const float*)d_in[2];
  const float* f2   = (const float*)d_in[3];
  const float* f3   = (const float*)d_in[4];
  const float* core = (const float*)d_in[5];
  const float* ofac = (const float*)d_in[6];
  const float* bias = (const float*)d_in[7];
  float* out = (float*)d_out;
  float* ws = (float*)d_ws;

  float* A  = ws;
  float* B  = ws + 262144;
  float* T4 = ws + 524288;

  k_g01<<<64, 256, 0, stream>>>(f0, f1, A);
  k_g23<<<64, 256, 0, stream>>>(f2, f3, B);
  k_t4<<<1024, 256, 0, stream>>>(A, B, core, T4);

  if (ws_size >= WS_NEED) {
    unsigned short* Bp = (unsigned short*)(ws + 786432);
    float* Ypart = ws + 1048576;            // 16 x 262144 floats
    k_pack<<<128, 256, 0, stream>>>(T4, Bp);
    k_ymm<<<1024, 256, 0, stream>>>(x, Bp, Ypart);
    k_out2<<<256, 256, 0, stream>>>(Ypart, ofac, bias, out);
  } else {
    float* Yb = ws + 786432;
    k_y<<<256, 256, 0, stream>>>(x, T4, Yb);
    k_out<<<256, 256, 0, stream>>>(Yb, ofac, bias, out);
  }
}

// Round 6
// 188.170 us; speedup vs baseline: 2.0802x; 1.2219x over previous
//
#include <hip/hip_runtime.h>

// Tensor-ring layer v4 — all heavy contractions on MFMA (bf16 hi/lo split, 3 products).
// Fragment conventions (validated on-device in round 3):
//   A[m][k]: lane l holds m = m0+(l&15), k = k0 + 8*(l>>4)+j   (short8v, j=0..8)
//   B[k][n]: lane l holds n = n0+(l&15), same k map
//   D[m][n]: lane l holds n = n0+(l&15), m = m0 + 4*(l>>4)+r   (f32x4)
// Pipeline:
//   k_build : G01[ij][ac*64+pq], G23[kl][ac*64+st]  (raw, 1 MB each)
//   k_packs : G01p (A-frag), CP (core B-frag), G23p (A-frag, k-order st*64+ac)
//   per o-half h: k_dmat: D = G01 @ core  -> Dp (bf16 hi/lo, GEMM-C B-frag layout)
//                 k_t4mm: T4part[kc] += G23 @ D_ij (split-K x8, no atomics)
//   k_pack2 : reduce 8 partials -> Bp (x-GEMM B-frag, bf16 hi/lo)
//   k_ymm   : Y = x @ T4 (round-3 kernel, validated), split-K x16 partials
//   k_yred  : reduce 16 partials -> Yp (A-frag) ; pack OF -> OFp (B-frag)
//   k_out3  : out = Y @ OF + bias (MFMA)
// ws f32 offsets: G01 0 | G23 262144 | G01p 524288 | CP 786432 | G23p 1048576
//   | Bp 1310720 | Yp 1572864 | OFp 1835008 | T4part 1900544 (2097152)
//   | Dp 3997696 (8388608; Ypart aliases here) | end 12386304 (49.5 MB)

#define WS_NEED ((size_t)12386304 * 4)

typedef __attribute__((ext_vector_type(8))) short short8v;
typedef __attribute__((ext_vector_type(4))) float f32x4;

__device__ inline unsigned short f2bf(float f) {
  unsigned u = __builtin_bit_cast(unsigned, f);
  u += 0x7FFFu + ((u >> 16) & 1u);
  return (unsigned short)(u >> 16);
}
__device__ inline float bf2f(unsigned short h) {
  return __builtin_bit_cast(float, (unsigned)h << 16);
}

// ---------------- G01 / G23 build ----------------

__global__ __launch_bounds__(256) void k_build(const float* __restrict__ f0,
                                               const float* __restrict__ f1,
                                               const float* __restrict__ f2,
                                               const float* __restrict__ f3,
                                               float* __restrict__ G01,
                                               float* __restrict__ G23) {
  int bb = blockIdx.x, tid = threadIdx.x;
  __shared__ float lu[512], lv[512];
  bool is01 = bb < 64;
  int pairi = is01 ? bb : bb - 64;
  int iA = pairi >> 3, iB = pairi & 7;
  const float* fu = is01 ? f0 : f2;
  const float* fv = is01 ? f1 : f3;
  if (tid < 128)
    reinterpret_cast<float4*>(lu)[tid] = reinterpret_cast<const float4*>(fu + iA * 512)[tid];
  else
    reinterpret_cast<float4*>(lv)[tid - 128] = reinterpret_cast<const float4*>(fv + iB * 512)[tid - 128];
  __syncthreads();
  float* dst = is01 ? G01 : G23;
#pragma unroll
  for (int r = 0; r < 16; ++r) {
    int idx = r * 256 + tid;
    int uv = idx >> 6, pq = idx & 63;    // uv = ac, pq (or st)
    int a = uv >> 3, c = uv & 7, p = pq >> 3, q = pq & 7;
    float acc = 0.f;
    if (is01) {
#pragma unroll
      for (int b = 0; b < 8; ++b)
        acc = fmaf(lu[a * 64 + b * 8 + p], lv[b * 64 + c * 8 + q], acc);
    } else {                             // a,c ring links; p->s, q->t
#pragma unroll
      for (int d = 0; d < 8; ++d)
        acc = fmaf(lu[c * 64 + d * 8 + p], lv[d * 64 + a * 8 + q], acc);
    }
    dst[pairi * 4096 + idx] = acc;
  }
}

// ---------------- pack G01p / CP / G23p ----------------

__global__ __launch_bounds__(256) void k_packs(const float* __restrict__ G01,
                                               const float* __restrict__ G23,
                                               const float* __restrict__ core,
                                               unsigned short* __restrict__ G01p,
                                               unsigned short* __restrict__ CP,
                                               unsigned short* __restrict__ G23p) {
  int bb = blockIdx.x, tid = threadIdx.x;
  __shared__ float ls[4096];
  if (bb < 64) {                          // G01p: A-frag of GEMM-B, ij = bb
    int ij = bb;
#pragma unroll
    for (int r = 0; r < 4; ++r)
      reinterpret_cast<float4*>(ls)[r * 256 + tid] =
          reinterpret_cast<const float4*>(G01 + ij * 4096)[r * 256 + tid];
    __syncthreads();
    short8v* dst = reinterpret_cast<short8v*>(G01p);
#pragma unroll
    for (int it = 0; it < 2; ++it) {
      int item = it * 256 + tid;          // ks(2)*mf(4)*l(64)
      int ks = item >> 8, mf = (item >> 6) & 3, l = item & 63;
      short8v hi, lo;
#pragma unroll
      for (int j = 0; j < 8; ++j) {
        float v = ls[(mf * 16 + (l & 15)) * 64 + ks * 32 + 8 * (l >> 4) + j];
        unsigned short h = f2bf(v);
        hi[j] = (short)h; lo[j] = (short)f2bf(v - bf2f(h));
      }
      size_t base = ((((size_t)ij * 2 + ks) * 4 + mf) * 2) * 64 + l;
      dst[base] = hi; dst[base + 64] = lo;
    }
  } else if (bb < 128) {                  // CP: B-frag of GEMM-B, st = bb-64
    int st = bb - 64;
#pragma unroll
    for (int r = 0; r < 4; ++r) {
      int f4 = r * 256 + tid;             // pq = f4>>4, o4 = f4&15
      reinterpret_cast<float4*>(ls)[f4] =
          reinterpret_cast<const float4*>(core)[(f4 >> 4) * 1024 + st * 16 + (f4 & 15)];
    }
    __syncthreads();
    short8v* dst = reinterpret_cast<short8v*>(CP);
#pragma unroll
    for (int it = 0; it < 2; ++it) {
      int item = it * 256 + tid;          // ks(2)*nf(4)*l(64)
      int ks = item >> 8, nf = (item >> 6) & 3, l = item & 63;
      short8v hi, lo;
#pragma unroll
      for (int j = 0; j < 8; ++j) {
        float v = ls[(ks * 32 + 8 * (l >> 4) + j) * 64 + nf * 16 + (l & 15)];
        unsigned short h = f2bf(v);
        hi[j] = (short)h; lo[j] = (short)f2bf(v - bf2f(h));
      }
      size_t base = ((((size_t)st * 2 + ks) * 4 + nf) * 2) * 64 + l;
      dst[base] = hi; dst[base + 64] = lo;
    }
  } else {                                // G23p: A-frag of GEMM-C, ks = bb-128
    int ks = bb - 128;                    // k2 = st*64+ac ; st = ks>>1, ac = (ks&1)*32 + koff
    int st = ks >> 1, acb = (ks & 1) * 32;
#pragma unroll
    for (int r = 0; r < 8; ++r) {
      int idx = r * 256 + tid;            // kl = idx>>5, a = idx&31
      ls[idx] = G23[(idx >> 5) * 4096 + (acb + (idx & 31)) * 64 + st];
    }
    __syncthreads();
    short8v* dst = reinterpret_cast<short8v*>(G23p);
    int mf = tid >> 6, l = tid & 63;
    short8v hi, lo;
#pragma unroll
    for (int j = 0; j < 8; ++j) {
      float v = ls[(mf * 16 + (l & 15)) * 32 + 8 * (l >> 4) + j];
      unsigned short h = f2bf(v);
      hi[j] = (short)h; lo[j] = (short)f2bf(v - bf2f(h));
    }
    size_t base = (((size_t)ks * 4 + mf) * 2) * 64 + l;
    dst[base] = hi; dst[base + 64] = lo;
  }
}

// ---------------- GEMM-B: D = G01 @ core, emit Dp in GEMM-C B-frag layout ----------------

__global__ __launch_bounds__(256) void k_dmat(const unsigned short* __restrict__ G01p,
                                              const unsigned short* __restrict__ CP,
                                              unsigned short* __restrict__ Dp,
                                              int h) {
  int bid = blockIdx.x;                   // 4096: ij*64 + st
  int ij = bid >> 6, st = bid & 63;
  int w = threadIdx.x >> 6, l = threadIdx.x & 63;
  const short8v* gp = reinterpret_cast<const short8v*>(G01p);
  const short8v* cp = reinterpret_cast<const short8v*>(CP);
  short8v ah0 = gp[((((size_t)ij * 2 + 0) * 4 + w) * 2) * 64 + l];
  short8v al0 = gp[((((size_t)ij * 2 + 0) * 4 + w) * 2) * 64 + 64 + l];
  short8v ah1 = gp[((((size_t)ij * 2 + 1) * 4 + w) * 2) * 64 + l];
  short8v al1 = gp[((((size_t)ij * 2 + 1) * 4 + w) * 2) * 64 + 64 + l];
  f32x4 acc[2];
  acc[0] = (f32x4){0.f, 0.f, 0.f, 0.f};
  acc[1] = acc[0];
#pragma unroll
  for (int n2 = 0; n2 < 2; ++n2) {
    int nf = 2 * h + n2;
    short8v bh0 = cp[((((size_t)st * 2 + 0) * 4 + nf) * 2) * 64 + l];
    short8v bl0 = cp[((((size_t)st * 2 + 0) * 4 + nf) * 2) * 64 + 64 + l];
    short8v bh1 = cp[((((size_t)st * 2 + 1) * 4 + nf) * 2) * 64 + l];
    short8v bl1 = cp[((((size_t)st * 2 + 1) * 4 + nf) * 2) * 64 + 64 + l];
    acc[n2] = __builtin_amdgcn_mfma_f32_16x16x32_bf16(ah0, bh0, acc[n2], 0, 0, 0);
    acc[n2] = __builtin_amdgcn_mfma_f32_16x16x32_bf16(al0, bh0, acc[n2], 0, 0, 0);
    acc[n2] = __builtin_amdgcn_mfma_f32_16x16x32_bf16(ah0, bl0, acc[n2], 0, 0, 0);
    acc[n2] = __builtin_amdgcn_mfma_f32_16x16x32_bf16(ah1, bh1, acc[n2], 0, 0, 0);
    acc[n2] = __builtin_amdgcn_mfma_f32_16x16x32_bf16(al1, bh1, acc[n2], 0, 0, 0);
    acc[n2] = __builtin_amdgcn_mfma_f32_16x16x32_bf16(ah1, bl1, acc[n2], 0, 0, 0);
  }
  __shared__ float lds[64 * 34];          // [ac][o'], stride 34 vs bank conflicts
#pragma unroll
  for (int n2 = 0; n2 < 2; ++n2)
#pragma unroll
    for (int r = 0; r < 4; ++r)
      lds[(w * 16 + 4 * (l >> 4) + r) * 34 + n2 * 16 + (l & 15)] = acc[n2][r];
  __syncthreads();
  // pack: thread = a2(2) * n2p(2) * l2(64)
  int t = threadIdx.x;
  int a2 = t >> 7, n2p = (t >> 6) & 1, l2 = t & 63;
  short8v hi, lo;
#pragma unroll
  for (int j = 0; j < 8; ++j) {
    float v = lds[(a2 * 32 + 8 * (l2 >> 4) + j) * 34 + n2p * 16 + (l2 & 15)];
    unsigned short hh = f2bf(v);
    hi[j] = (short)hh; lo[j] = (short)f2bf(v - bf2f(hh));
  }
  short8v* dst = reinterpret_cast<short8v*>(Dp);
  size_t base = ((((size_t)ij * 128 + st * 2 + a2) * 2 + n2p) * 2) * 64 + l2;
  dst[base] = hi; dst[base + 64] = lo;
}

// ---------------- GEMM-C: T4part[kc] = G23 @ D_ij (split-K x8) ----------------

__global__ __launch_bounds__(256) void k_t4mm(const unsigned short* __restrict__ G23p,
                                              const unsigned short* __restrict__ Dp,
                                              float* __restrict__ T4part,
                                              int h) {
  int bid = blockIdx.x;                   // 512: ij*8 + kc
  int ij = bid >> 3, kc = bid & 7;
  int w = threadIdx.x >> 6, l = threadIdx.x & 63;
  const short8v* ga = reinterpret_cast<const short8v*>(G23p);
  const short8v* gb = reinterpret_cast<const short8v*>(Dp);
  f32x4 acc0 = {0.f, 0.f, 0.f, 0.f}, acc1 = acc0;
#pragma unroll 2
  for (int ks = kc * 16; ks < kc * 16 + 16; ++ks) {
    size_t abase = (((size_t)ks * 4 + w) * 2) * 64 + l;
    short8v ah = ga[abase], al = ga[abase + 64];
    size_t bbase = (((size_t)ij * 128 + ks) * 4) * 64 + l;
    short8v bh0 = gb[bbase],       bl0 = gb[bbase + 64];
    short8v bh1 = gb[bbase + 128], bl1 = gb[bbase + 192];
    acc0 = __builtin_amdgcn_mfma_f32_16x16x32_bf16(ah, bh0, acc0, 0, 0, 0);
    acc0 = __builtin_amdgcn_mfma_f32_16x16x32_bf16(al, bh0, acc0, 0, 0, 0);
    acc0 = __builtin_amdgcn_mfma_f32_16x16x32_bf16(ah, bl0, acc0, 0, 0, 0);
    acc1 = __builtin_amdgcn_mfma_f32_16x16x32_bf16(ah, bh1, acc1, 0, 0, 0);
    acc1 = __builtin_amdgcn_mfma_f32_16x16x32_bf16(al, bh1, acc1, 0, 0, 0);
    acc1 = __builtin_amdgcn_mfma_f32_16x16x32_bf16(ah, bl1, acc1, 0, 0, 0);
  }
#pragma unroll
  for (int r = 0; r < 4; ++r) {
    int row = w * 16 + 4 * (l >> 4) + r;
    T4part[(((size_t)kc * 64 + ij) * 64 + row) * 64 + h * 32 + (l & 15)] = acc0[r];
    T4part[(((size_t)kc * 64 + ij) * 64 + row) * 64 + h * 32 + 16 + (l & 15)] = acc1[r];
  }
}

// ---------------- reduce T4 partials + pack x-GEMM B-frag ----------------

__global__ __launch_bounds__(256) void k_pack2(const float* __restrict__ T4part,
                                               unsigned short* __restrict__ Bp) {
  int kb = blockIdx.x, tid = threadIdx.x; // 128 blocks, rows kb*32..+32
  __shared__ float ls[2048];
  f32x4 a0 = {0.f, 0.f, 0.f, 0.f}, a1 = a0;
#pragma unroll
  for (int kc = 0; kc < 8; ++kc) {
    const f32x4* src = reinterpret_cast<const f32x4*>(T4part + (size_t)kc * 262144 + kb * 2048);
    a0 += src[tid];
    a1 += src[256 + tid];
  }
  reinterpret_cast<f32x4*>(ls)[tid] = a0;
  reinterpret_cast<f32x4*>(ls)[256 + tid] = a1;
  __syncthreads();
  short8v* dst = reinterpret_cast<short8v*>(Bp);
  int nf = tid >> 6, l = tid & 63;
  short8v hi, lo;
#pragma unroll
  for (int j = 0; j < 8; ++j) {
    float v = ls[(8 * (l >> 4) + j) * 64 + nf * 16 + (l & 15)];
    unsigned short h = f2bf(v);
    hi[j] = (short)h; lo[j] = (short)f2bf(v - bf2f(h));
  }
  size_t base = (size_t)kb * 512 + (nf * 2) * 64 + l;
  dst[base] = hi; dst[base + 64] = lo;
}

// ---------------- Y = x @ T4 (round-3 validated) ----------------

__global__ __launch_bounds__(256) void k_ymm(const float* __restrict__ x,
                                             const unsigned short* __restrict__ Bp,
                                             float* __restrict__ Ypart) {
  int mt = blockIdx.x >> 4, kc = blockIdx.x & 15;
  int w = threadIdx.x >> 6, l = threadIdx.x & 63;
  int kg = l >> 4, lm = l & 15;
  const float4* xp = reinterpret_cast<const float4*>(
      x + (size_t)(mt * 64 + w * 16 + lm) * 4096 + kc * 256 + kg * 8);
  f32x4 acc0 = {0.f, 0.f, 0.f, 0.f}, acc1 = acc0, acc2 = acc0, acc3 = acc0;
#pragma unroll 1
  for (int s = 0; s < 8; ++s) {
    float4 xa = xp[s * 8], xb = xp[s * 8 + 1];
    float xs[8] = {xa.x, xa.y, xa.z, xa.w, xb.x, xb.y, xb.z, xb.w};
    short8v ah, al;
#pragma unroll
    for (int j = 0; j < 8; ++j) {
      unsigned short h = f2bf(xs[j]);
      ah[j] = (short)h;
      al[j] = (short)f2bf(xs[j] - bf2f(h));
    }
    const short8v* bp = reinterpret_cast<const short8v*>(Bp + (size_t)(kc * 8 + s) * 4096) + l;
    short8v bh0 = bp[0],   bl0 = bp[64];
    short8v bh1 = bp[128], bl1 = bp[192];
    short8v bh2 = bp[256], bl2 = bp[320];
    short8v bh3 = bp[384], bl3 = bp[448];
    acc0 = __builtin_amdgcn_mfma_f32_16x16x32_bf16(ah, bh0, acc0, 0, 0, 0);
    acc1 = __builtin_amdgcn_mfma_f32_16x16x32_bf16(ah, bh1, acc1, 0, 0, 0);
    acc2 = __builtin_amdgcn_mfma_f32_16x16x32_bf16(ah, bh2, acc2, 0, 0, 0);
    acc3 = __builtin_amdgcn_mfma_f32_16x16x32_bf16(ah, bh3, acc3, 0, 0, 0);
    acc0 = __builtin_amdgcn_mfma_f32_16x16x32_bf16(al, bh0, acc0, 0, 0, 0);
    acc1 = __builtin_amdgcn_mfma_f32_16x16x32_bf16(al, bh1, acc1, 0, 0, 0);
    acc2 = __builtin_amdgcn_mfma_f32_16x16x32_bf16(al, bh2, acc2, 0, 0, 0);
    acc3 = __builtin_amdgcn_mfma_f32_16x16x32_bf16(al, bh3, acc3, 0, 0, 0);
    acc0 = __builtin_amdgcn_mfma_f32_16x16x32_bf16(ah, bl0, acc0, 0, 0, 0);
    acc1 = __builtin_amdgcn_mfma_f32_16x16x32_bf16(ah, bl1, acc1, 0, 0, 0);
    acc2 = __builtin_amdgcn_mfma_f32_16x16x32_bf16(ah, bl2, acc2, 0, 0, 0);
    acc3 = __builtin_amdgcn_mfma_f32_16x16x32_bf16(ah, bl3, acc3, 0, 0, 0);
  }
  float* yb = Ypart + (size_t)kc * 262144 + (size_t)(mt * 64 + w * 16) * 64;
#pragma unroll
  for (int r = 0; r < 4; ++r) {
    yb[(kg * 4 + r) * 64 + 0  + lm] = acc0[r];
    yb[(kg * 4 + r) * 64 + 16 + lm] = acc1[r];
    yb[(kg * 4 + r) * 64 + 32 + lm] = acc2[r];
    yb[(kg * 4 + r) * 64 + 48 + lm] = acc3[r];
  }
}

// ---------------- reduce Ypart -> Yp (A-frag); pack OF -> OFp (B-frag) ----------------

__global__ __launch_bounds__(256) void k_yred(const float* __restrict__ Ypart,
                                              const float* __restrict__ OF_,
                                              unsigned short* __restrict__ Yp,
                                              unsigned short* __restrict__ OFp) {
  int bb = blockIdx.x, tid = threadIdx.x;
  __shared__ float ls[8192];
  if (bb < 64) {                          // Y-reduce + A-frag pack, rows bb*64..+64
    f32x4 a[4];
#pragma unroll
    for (int r = 0; r < 4; ++r) a[r] = (f32x4){0.f, 0.f, 0.f, 0.f};
#pragma unroll
    for (int kc = 0; kc < 16; ++kc) {
      const f32x4* src = reinterpret_cast<const f32x4*>(Ypart + (size_t)kc * 262144 + (size_t)bb * 4096);
#pragma unroll
      for (int r = 0; r < 4; ++r) a[r] += src[r * 256 + tid];
    }
#pragma unroll
    for (int r = 0; r < 4; ++r) reinterpret_cast<f32x4*>(ls)[r * 256 + tid] = a[r];
    __syncthreads();
    short8v* dst = reinterpret_cast<short8v*>(Yp);
#pragma unroll
    for (int it = 0; it < 2; ++it) {
      int item = it * 256 + tid;          // mtl(4)*ks(2)*l(64)
      int mtl = item >> 7, ks = (item >> 6) & 1, l = item & 63;
      short8v hi, lo;
#pragma unroll
      for (int j = 0; j < 8; ++j) {
        float v = ls[(mtl * 16 + (l & 15)) * 64 + ks * 32 + 8 * (l >> 4) + j];
        unsigned short h = f2bf(v);
        hi[j] = (short)h; lo[j] = (short)f2bf(v - bf2f(h));
      }
      int mtu = bb * 4 + mtl;
      size_t base = (((size_t)mtu * 2 + ks) * 2) * 64 + l;
      dst[base] = hi; dst[base + 64] = lo;
    }
  } else {                                // OFp: 8 blocks, nf group g = bb-64
    int g = bb - 64;
#pragma unroll
    for (int it = 0; it < 8; ++it) {
      int f4 = it * 256 + tid;            // o = f4>>5, c4 = f4&31
      reinterpret_cast<float4*>(ls)[f4] =
          reinterpret_cast<const float4*>(OF_)[(f4 >> 5) * 256 + g * 32 + (f4 & 31)];
    }
    __syncthreads();
    short8v* dst = reinterpret_cast<short8v*>(OFp);
#pragma unroll
    for (int it = 0; it < 4; ++it) {
      int item = it * 256 + tid;          // nfl(8)*ks(2)*l(64)
      int nfl = item >> 7, ks = (item >> 6) & 1, l = item & 63;
      short8v hi, lo;
#pragma unroll
      for (int j = 0; j < 8; ++j) {
        float v = ls[(ks * 32 + 8 * (l >> 4) + j) * 128 + nfl * 16 + (l & 15)];
        unsigned short h = f2bf(v);
        hi[j] = (short)h; lo[j] = (short)f2bf(v - bf2f(h));
      }
      int nfg = g * 8 + nfl;
      size_t base = (((size_t)nfg * 2 + ks) * 2) * 64 + l;
      dst[base] = hi; dst[base + 64] = lo;
    }
  }
}

// ---------------- out = Y @ OF + bias (MFMA) ----------------

__global__ __launch_bounds__(256) void k_out3(const unsigned short* __restrict__ Yp,
                                              const unsigned short* __restrict__ OFp,
                                              const float* __restrict__ bias,
                                              float* __restrict__ out) {
  int bid = blockIdx.x;                   // 256: mtile(64) * nch(4)
  int mtile = bid >> 2, nch = bid & 3;
  int w = threadIdx.x >> 6, l = threadIdx.x & 63;
  int mtu = mtile * 4 + w;
  const short8v* yp = reinterpret_cast<const short8v*>(Yp);
  const short8v* op = reinterpret_cast<const short8v*>(OFp);
  short8v ya0 = yp[(((size_t)mtu * 2 + 0) * 2) * 64 + l];
  short8v yl0 = yp[(((size_t)mtu * 2 + 0) * 2) * 64 + 64 + l];
  short8v ya1 = yp[(((size_t)mtu * 2 + 1) * 2) * 64 + l];
  short8v yl1 = yp[(((size_t)mtu * 2 + 1) * 2) * 64 + 64 + l];
#pragma unroll 4
  for (int nf = 0; nf < 16; ++nf) {
    int nfg = nch * 16 + nf;
    size_t bb = (((size_t)nfg * 2) * 2) * 64 + l;
    short8v bh0 = op[bb], bl0 = op[bb + 64], bh1 = op[bb + 128], bl1 = op[bb + 192];
    f32x4 acc = {0.f, 0.f, 0.f, 0.f};
    acc = __builtin_amdgcn_mfma_f32_16x16x32_bf16(ya0, bh0, acc, 0, 0, 0);
    acc = __builtin_amdgcn_mfma_f32_16x16x32_bf16(yl0, bh0, acc, 0, 0, 0);
    acc = __builtin_amdgcn_mfma_f32_16x16x32_bf16(ya0, bl0, acc, 0, 0, 0);
    acc = __builtin_amdgcn_mfma_f32_16x16x32_bf16(ya1, bh1, acc, 0, 0, 0);
    acc = __builtin_amdgcn_mfma_f32_16x16x32_bf16(yl1, bh1, acc, 0, 0, 0);
    acc = __builtin_amdgcn_mfma_f32_16x16x32_bf16(ya1, bl1, acc, 0, 0, 0);
    float bv = bias[nfg * 16 + (l & 15)];
#pragma unroll
    for (int r = 0; r < 4; ++r)
      out[(size_t)(mtile * 64 + w * 16 + 4 * (l >> 4) + r) * 1024 + nfg * 16 + (l & 15)] = acc[r] + bv;
  }
}

// ---------------- fallback (round-1 verified path) ----------------

__global__ __launch_bounds__(256) void k_t4(const float* __restrict__ A,
                                            const float* __restrict__ B,
                                            const float* __restrict__ core,
                                            float* __restrict__ T4) {
  int bid = blockIdx.x;
  int ij = bid >> 4, kl0 = (bid & 15) * 4;
  __shared__ float lA[4096];
  __shared__ float lS[4][4096];
  int tid = threadIdx.x;
#pragma unroll
  for (int r = 0; r < 4; ++r)
    reinterpret_cast<float4*>(lA)[r * 256 + tid] =
        reinterpret_cast<const float4*>(A + ij * 4096)[r * 256 + tid];
  __syncthreads();
  int pq0 = (tid >> 4) << 2;
  int st04 = tid & 15;
#pragma unroll 1
  for (int m = 0; m < 4; ++m) {
    const float4* Bp = reinterpret_cast<const float4*>(B + (kl0 + m) * 4096);
    float acc[4][4] = {{0.f}};
    for (int ac = 0; ac < 64; ++ac) {
      float4 av = reinterpret_cast<float4*>(lA)[ac * 16 + (pq0 >> 2)];
      float4 bv = Bp[ac * 16 + st04];
      float au[4] = {av.x, av.y, av.z, av.w};
      float bu[4] = {bv.x, bv.y, bv.z, bv.w};
#pragma unroll
      for (int u = 0; u < 4; ++u)
#pragma unroll
        for (int v = 0; v < 4; ++v)
          acc[u][v] = fmaf(au[u], bu[v], acc[u][v]);
    }
    float4* S4 = reinterpret_cast<float4*>(lS[m]);
#pragma unroll
    for (int u = 0; u < 4; ++u)
      S4[(pq0 + u) * 16 + st04] = make_float4(acc[u][0], acc[u][1], acc[u][2], acc[u][3]);
  }
  __syncthreads();
  int o44 = tid & 15, seg = tid >> 4;
  const float4* c4 = reinterpret_cast<const float4*>(core);
  float4 r0 = {0, 0, 0, 0}, r1 = r0, r2 = r0, r3 = r0;
  for (int n = 0; n < 256; ++n) {
    int midx = seg * 256 + n;
    float4 cv = c4[midx * 16 + o44];
    float s0 = lS[0][midx], s1 = lS[1][midx], s2 = lS[2][midx], s3 = lS[3][midx];
    r0.x = fmaf(s0, cv.x, r0.x); r0.y = fmaf(s0, cv.y, r0.y);
    r0.z = fmaf(s0, cv.z, r0.z); r0.w = fmaf(s0, cv.w, r0.w);
    r1.x = fmaf(s1, cv.x, r1.x); r1.y = fmaf(s1, cv.y, r1.y);
    r1.z = fmaf(s1, cv.z, r1.z); r1.w = fmaf(s1, cv.w, r1.w);
    r2.x = fmaf(s2, cv.x, r2.x); r2.y = fmaf(s2, cv.y, r2.y);
    r2.z = fmaf(s2, cv.z, r2.z); r2.w = fmaf(s2, cv.w, r2.w);
    r3.x = fmaf(s3, cv.x, r3.x); r3.y = fmaf(s3, cv.y, r3.y);
    r3.z = fmaf(s3, cv.z, r3.z); r3.w = fmaf(s3, cv.w, r3.w);
  }
  float4* red = reinterpret_cast<float4*>(lA);
  red[(seg * 4 + 0) * 16 + o44] = r0;
  red[(seg * 4 + 1) * 16 + o44] = r1;
  red[(seg * 4 + 2) * 16 + o44] = r2;
  red[(seg * 4 + 3) * 16 + o44] = r3;
  __syncthreads();
  int m2 = tid >> 6, o = tid & 63;
  float t = 0.f;
#pragma unroll
  for (int s2 = 0; s2 < 16; ++s2) t += lA[(s2 * 4 + m2) * 64 + o];
  T4[(ij * 64 + kl0 + m2) * 64 + o] = t;
}

__global__ __launch_bounds__(256) void k_y(const float* __restrict__ x,
                                           const float* __restrict__ T4,
                                           float* __restrict__ Y) {
  int b0 = blockIdx.x * 16;
  __shared__ float lx[1024];
  int tid = threadIdx.x;
  int o = tid & 63, rg = tid >> 6;
  float acc0 = 0.f, acc1 = 0.f, acc2 = 0.f, acc3 = 0.f;
  const float4* lx4 = reinterpret_cast<const float4*>(lx);
  for (int kc = 0; kc < 4096; kc += 64) {
    __syncthreads();
    reinterpret_cast<float4*>(lx)[tid] =
        *reinterpret_cast<const float4*>(x + (b0 + (tid >> 4)) * 4096 + kc + (tid & 15) * 4);
    __syncthreads();
#pragma unroll 4
    for (int kk = 0; kk < 64; kk += 4) {
      float c0 = T4[(kc + kk + 0) * 64 + o];
      float c1 = T4[(kc + kk + 1) * 64 + o];
      float c2 = T4[(kc + kk + 2) * 64 + o];
      float c3 = T4[(kc + kk + 3) * 64 + o];
      float4 xv;
      xv = lx4[(rg * 4 + 0) * 16 + (kk >> 2)];
      acc0 = fmaf(xv.x, c0, fmaf(xv.y, c1, fmaf(xv.z, c2, fmaf(xv.w, c3, acc0))));
      xv = lx4[(rg * 4 + 1) * 16 + (kk >> 2)];
      acc1 = fmaf(xv.x, c0, fmaf(xv.y, c1, fmaf(xv.z, c2, fmaf(xv.w, c3, acc1))));
      xv = lx4[(rg * 4 + 2) * 16 + (kk >> 2)];
      acc2 = fmaf(xv.x, c0, fmaf(xv.y, c1, fmaf(xv.z, c2, fmaf(xv.w, c3, acc2))));
      xv = lx4[(rg * 4 + 3) * 16 + (kk >> 2)];
      acc3 = fmaf(xv.x, c0, fmaf(xv.y, c1, fmaf(xv.z, c2, fmaf(xv.w, c3, acc3))));
    }
  }
  Y[(b0 + rg * 4 + 0) * 64 + o] = acc0;
  Y[(b0 + rg * 4 + 1) * 64 + o] = acc1;
  Y[(b0 + rg * 4 + 2) * 64 + o] = acc2;
  Y[(b0 + rg * 4 + 3) * 64 + o] = acc3;
}

__global__ __launch_bounds__(256) void k_out(const float* __restrict__ Y,
                                             const float* __restrict__ OF_,
                                             const float* __restrict__ bias,
                                             float* __restrict__ out) {
  int b0 = blockIdx.x * 16;
  int tid = threadIdx.x;
  __shared__ float lY[1024];
  reinterpret_cast<float4*>(lY)[tid] =
      *reinterpret_cast<const float4*>(Y + (b0 + (tid >> 4)) * 64 + (tid & 15) * 4);
  __syncthreads();
  float4 acc[16];
#pragma unroll
  for (int r = 0; r < 16; ++r) acc[r] = make_float4(0.f, 0.f, 0.f, 0.f);
  for (int oo = 0; oo < 64; ++oo) {
    float4 w = *reinterpret_cast<const float4*>(OF_ + oo * 1024 + tid * 4);
#pragma unroll
    for (int r = 0; r < 16; ++r) {
      float yv = lY[r * 64 + oo];
      acc[r].x = fmaf(yv, w.x, acc[r].x);
      acc[r].y = fmaf(yv, w.y, acc[r].y);
      acc[r].z = fmaf(yv, w.z, acc[r].z);
      acc[r].w = fmaf(yv, w.w, acc[r].w);
    }
  }
  float4 bv = *reinterpret_cast<const float4*>(bias + tid * 4);
#pragma unroll
  for (int r = 0; r < 16; ++r) {
    float4 v = acc[r];
    v.x += bv.x; v.y += bv.y; v.z += bv.z; v.w += bv.w;
    *reinterpret_cast<float4*>(out + (b0 + r) * 1024 + tid * 4) = v;
  }
}

// ---------------- host ----------------

extern "C" void kernel_launch(void* const* d_in, const int* in_sizes, int n_in,
                              void* d_out, int out_size, void* d_ws, size_t ws_size,
                              hipStream_t stream) {
  const float* x    = (const float*)d_in[0];
  const float* f0   = (const float*)d_in[1];
  const float* f1   = (const float*)d_in[2];
  const float* f2   = (const float*)d_in[3];
  const float* f3   = (const float*)d_in[4];
  const float* core = (const float*)d_in[5];
  const float* ofac = (const float*)d_in[6];
  const float* bias = (const float*)d_in[7];
  float* out = (float*)d_out;
  float* ws = (float*)d_ws;

  float* G01 = ws;
  float* G23 = ws + 262144;

  k_build<<<128, 256, 0, stream>>>(f0, f1, f2, f3, G01, G23);

  if (ws_size >= WS_NEED) {
    unsigned short* G01p = (unsigned short*)(ws + 524288);
    unsigned short* CP   = (unsigned short*)(ws + 786432);
    unsigned short* G23p = (unsigned short*)(ws + 1048576);
    unsigned short* Bp   = (unsigned short*)(ws + 1310720);
    unsigned short* Yp   = (unsigned short*)(ws + 1572864);
    unsigned short* OFp  = (unsigned short*)(ws + 1835008);
    float* T4part = ws + 1900544;
    unsigned short* Dp = (unsigned short*)(ws + 3997696);
    float* Ypart = ws + 3997696;          // aliases Dp (dead by then)

    k_packs<<<256, 256, 0, stream>>>(G01, G23, core, G01p, CP, G23p);
    for (int h = 0; h < 2; ++h) {
      k_dmat<<<4096, 256, 0, stream>>>(G01p, CP, Dp, h);
      k_t4mm<<<512, 256, 0, stream>>>(G23p, Dp, T4part, h);
    }
    k_pack2<<<128, 256, 0, stream>>>(T4part, Bp);
    k_ymm<<<1024, 256, 0, stream>>>(x, Bp, Ypart);
    k_yred<<<72, 256, 0, stream>>>(Ypart, ofac, Yp, OFp);
    k_out3<<<256, 256, 0, stream>>>(Yp, OFp, bias, out);
  } else {
    float* T4 = ws + 524288;
    float* Yb = ws + 786432;
    k_t4<<<1024, 256, 0, stream>>>(G01, G23, core, T4);
    k_y<<<256, 256, 0, stream>>>(x, T4, Yb);
    k_out<<<256, 256, 0, stream>>>(Yb, ofac, bias, out);
  }
}

// Round 7
// 178.737 us; speedup vs baseline: 2.1899x; 1.0528x over previous
//
#include <hip/hip_runtime.h>

// Tensor-ring layer v5 — MFMA pipeline, single-pass Dp (ws proven ~268MB), 7 launches.
// Fragment conventions (validated on-device rounds 3-4):
//   A[m][k]: lane l holds m = m0+(l&15), k = k0 + 8*(l>>4)+j   (short8v)
//   B[k][n]: lane l holds n = n0+(l&15), same k map
//   D[m][n]: lane l holds n = n0+(l&15), m = m0 + 4*(l>>4)+r   (f32x4)
// Pipeline:
//   k_build : G01[ij][ac*64+pq], G23[kl][ac*64+st]
//   k_packs : G01p (A-frag), CP (core B-frag), G23p (A-frag, k2=st*64+ac), OFp (B-frag)
//   k_dmat  : D = G01 @ core  -> Dp (bf16 hi/lo, GEMM-C B-frag layout, ALL o)  [67MB]
//   k_t4mm  : T4part[kc] = G23 @ D_ij  (split-K x8, no atomics)
//   k_pack2 : reduce 8 partials -> Bp (x-GEMM B-frag)
//   k_ymm   : Ypart = x @ T4 (split-K x16, trunc-split conversions)
//   k_out4  : reduce Ypart + out = Y @ OF + bias (fused, MFMA)
// ws f32 offsets:
//   G01 0 | G23 262144 | G01p 524288 | CP 786432 | G23p 1310720 | Bp 1835008
//   | OFp 2097152 | T4part 2162688 (2097152) | Ypart 4259840 (4194304)
//   | Dp 8454144 (16777216) | end 25231360  (~101 MB)

#define WS_NEED ((size_t)25231360 * 4)

typedef __attribute__((ext_vector_type(8))) short short8v;
typedef __attribute__((ext_vector_type(4))) float f32x4;

__device__ inline unsigned short f2bf(float f) {       // RNE (pack paths)
  unsigned u = __builtin_bit_cast(unsigned, f);
  u += 0x7FFFu + ((u >> 16) & 1u);
  return (unsigned short)(u >> 16);
}
__device__ inline float bf2f(unsigned short h) {
  return __builtin_bit_cast(float, (unsigned)h << 16);
}

// ---------------- G01 / G23 build ----------------

__global__ __launch_bounds__(256) void k_build(const float* __restrict__ f0,
                                               const float* __restrict__ f1,
                                               const float* __restrict__ f2,
                                               const float* __restrict__ f3,
                                               float* __restrict__ G01,
                                               float* __restrict__ G23) {
  int bb = blockIdx.x, tid = threadIdx.x;
  __shared__ float lu[512], lv[512];
  bool is01 = bb < 64;
  int pairi = is01 ? bb : bb - 64;
  int iA = pairi >> 3, iB = pairi & 7;
  const float* fu = is01 ? f0 : f2;
  const float* fv = is01 ? f1 : f3;
  if (tid < 128)
    reinterpret_cast<float4*>(lu)[tid] = reinterpret_cast<const float4*>(fu + iA * 512)[tid];
  else
    reinterpret_cast<float4*>(lv)[tid - 128] = reinterpret_cast<const float4*>(fv + iB * 512)[tid - 128];
  __syncthreads();
  float* dst = is01 ? G01 : G23;
#pragma unroll
  for (int r = 0; r < 16; ++r) {
    int idx = r * 256 + tid;
    int uv = idx >> 6, pq = idx & 63;
    int a = uv >> 3, c = uv & 7, p = pq >> 3, q = pq & 7;
    float acc = 0.f;
    if (is01) {
#pragma unroll
      for (int b = 0; b < 8; ++b)
        acc = fmaf(lu[a * 64 + b * 8 + p], lv[b * 64 + c * 8 + q], acc);
    } else {
#pragma unroll
      for (int d = 0; d < 8; ++d)
        acc = fmaf(lu[c * 64 + d * 8 + p], lv[d * 64 + a * 8 + q], acc);
    }
    dst[pairi * 4096 + idx] = acc;
  }
}

// ---------------- pack G01p / CP / G23p / OFp ----------------

__global__ __launch_bounds__(256) void k_packs(const float* __restrict__ G01,
                                               const float* __restrict__ G23,
                                               const float* __restrict__ core,
                                               const float* __restrict__ OF_,
                                               unsigned short* __restrict__ G01p,
                                               unsigned short* __restrict__ CP,
                                               unsigned short* __restrict__ G23p,
                                               unsigned short* __restrict__ OFp) {
  int bb = blockIdx.x, tid = threadIdx.x;
  __shared__ float ls[8192];
  if (bb < 64) {                          // G01p: A-frag of GEMM-B, ij = bb
    int ij = bb;
#pragma unroll
    for (int r = 0; r < 4; ++r)
      reinterpret_cast<float4*>(ls)[r * 256 + tid] =
          reinterpret_cast<const float4*>(G01 + ij * 4096)[r * 256 + tid];
    __syncthreads();
    short8v* dst = reinterpret_cast<short8v*>(G01p);
#pragma unroll
    for (int it = 0; it < 2; ++it) {
      int item = it * 256 + tid;          // ks(2)*mf(4)*l(64)
      int ks = item >> 8, mf = (item >> 6) & 3, l = item & 63;
      short8v hi, lo;
#pragma unroll
      for (int j = 0; j < 8; ++j) {
        float v = ls[(mf * 16 + (l & 15)) * 64 + ks * 32 + 8 * (l >> 4) + j];
        unsigned short h = f2bf(v);
        hi[j] = (short)h; lo[j] = (short)f2bf(v - bf2f(h));
      }
      size_t base = ((((size_t)ij * 2 + ks) * 4 + mf) * 2) * 64 + l;
      dst[base] = hi; dst[base + 64] = lo;
    }
  } else if (bb < 128) {                  // CP: B-frag of GEMM-B, st = bb-64
    int st = bb - 64;
#pragma unroll
    for (int r = 0; r < 4; ++r) {
      int f4 = r * 256 + tid;             // pq = f4>>4, o4 = f4&15
      reinterpret_cast<float4*>(ls)[f4] =
          reinterpret_cast<const float4*>(core)[(f4 >> 4) * 1024 + st * 16 + (f4 & 15)];
    }
    __syncthreads();
    short8v* dst = reinterpret_cast<short8v*>(CP);
#pragma unroll
    for (int it = 0; it < 2; ++it) {
      int item = it * 256 + tid;          // ks(2)*nf(4)*l(64)
      int ks = item >> 8, nf = (item >> 6) & 3, l = item & 63;
      short8v hi, lo;
#pragma unroll
      for (int j = 0; j < 8; ++j) {
        float v = ls[(ks * 32 + 8 * (l >> 4) + j) * 64 + nf * 16 + (l & 15)];
        unsigned short h = f2bf(v);
        hi[j] = (short)h; lo[j] = (short)f2bf(v - bf2f(h));
      }
      size_t base = ((((size_t)st * 2 + ks) * 4 + nf) * 2) * 64 + l;
      dst[base] = hi; dst[base + 64] = lo;
    }
  } else if (bb < 256) {                  // G23p: A-frag of GEMM-C, ks = bb-128
    int ks = bb - 128;                    // k2 = st*64+ac ; st = ks>>1, ac = (ks&1)*32+koff
    int st = ks >> 1, acb = (ks & 1) * 32;
#pragma unroll
    for (int r = 0; r < 8; ++r) {
      int idx = r * 256 + tid;            // kl = idx>>5, a = idx&31
      ls[idx] = G23[(idx >> 5) * 4096 + (acb + (idx & 31)) * 64 + st];
    }
    __syncthreads();
    short8v* dst = reinterpret_cast<short8v*>(G23p);
    int mf = tid >> 6, l = tid & 63;
    short8v hi, lo;
#pragma unroll
    for (int j = 0; j < 8; ++j) {
      float v = ls[(mf * 16 + (l & 15)) * 32 + 8 * (l >> 4) + j];
      unsigned short h = f2bf(v);
      hi[j] = (short)h; lo[j] = (short)f2bf(v - bf2f(h));
    }
    size_t base = (((size_t)ks * 4 + mf) * 2) * 64 + l;
    dst[base] = hi; dst[base + 64] = lo;
  } else {                                // OFp: 8 blocks, f-group g = bb-256
    int g = bb - 256;
#pragma unroll
    for (int it = 0; it < 8; ++it) {
      int f4 = it * 256 + tid;            // o = f4>>5, c4 = f4&31
      reinterpret_cast<float4*>(ls)[f4] =
          reinterpret_cast<const float4*>(OF_)[(f4 >> 5) * 256 + g * 32 + (f4 & 31)];
    }
    __syncthreads();
    short8v* dst = reinterpret_cast<short8v*>(OFp);
#pragma unroll
    for (int it = 0; it < 4; ++it) {
      int item = it * 256 + tid;          // nfl(8)*ks(2)*l(64)
      int nfl = item >> 7, ks = (item >> 6) & 1, l = item & 63;
      short8v hi, lo;
#pragma unroll
      for (int j = 0; j < 8; ++j) {
        float v = ls[(ks * 32 + 8 * (l >> 4) + j) * 128 + nfl * 16 + (l & 15)];
        unsigned short h = f2bf(v);
        hi[j] = (short)h; lo[j] = (short)f2bf(v - bf2f(h));
      }
      int nfg = g * 8 + nfl;
      size_t base = (((size_t)nfg * 2 + ks) * 2) * 64 + l;
      dst[base] = hi; dst[base + 64] = lo;
    }
  }
}

// ---------------- GEMM-B: D = G01 @ core (all 64 o), emit Dp in GEMM-C B-frag ----------------

__global__ __launch_bounds__(256) void k_dmat(const unsigned short* __restrict__ G01p,
                                              const unsigned short* __restrict__ CP,
                                              unsigned short* __restrict__ Dp) {
  int bid = blockIdx.x;                   // 4096: ij*64 + st
  int ij = bid >> 6, st = bid & 63;
  int w = threadIdx.x >> 6, l = threadIdx.x & 63;
  const short8v* gp = reinterpret_cast<const short8v*>(G01p);
  const short8v* cp = reinterpret_cast<const short8v*>(CP);
  short8v ah0 = gp[((((size_t)ij * 2 + 0) * 4 + w) * 2) * 64 + l];
  short8v al0 = gp[((((size_t)ij * 2 + 0) * 4 + w) * 2) * 64 + 64 + l];
  short8v ah1 = gp[((((size_t)ij * 2 + 1) * 4 + w) * 2) * 64 + l];
  short8v al1 = gp[((((size_t)ij * 2 + 1) * 4 + w) * 2) * 64 + 64 + l];
  f32x4 acc[4];
#pragma unroll
  for (int nf = 0; nf < 4; ++nf) acc[nf] = (f32x4){0.f, 0.f, 0.f, 0.f};
#pragma unroll
  for (int nf = 0; nf < 4; ++nf) {
    short8v bh0 = cp[((((size_t)st * 2 + 0) * 4 + nf) * 2) * 64 + l];
    short8v bl0 = cp[((((size_t)st * 2 + 0) * 4 + nf) * 2) * 64 + 64 + l];
    short8v bh1 = cp[((((size_t)st * 2 + 1) * 4 + nf) * 2) * 64 + l];
    short8v bl1 = cp[((((size_t)st * 2 + 1) * 4 + nf) * 2) * 64 + 64 + l];
    acc[nf] = __builtin_amdgcn_mfma_f32_16x16x32_bf16(ah0, bh0, acc[nf], 0, 0, 0);
    acc[nf] = __builtin_amdgcn_mfma_f32_16x16x32_bf16(al0, bh0, acc[nf], 0, 0, 0);
    acc[nf] = __builtin_amdgcn_mfma_f32_16x16x32_bf16(ah0, bl0, acc[nf], 0, 0, 0);
    acc[nf] = __builtin_amdgcn_mfma_f32_16x16x32_bf16(ah1, bh1, acc[nf], 0, 0, 0);
    acc[nf] = __builtin_amdgcn_mfma_f32_16x16x32_bf16(al1, bh1, acc[nf], 0, 0, 0);
    acc[nf] = __builtin_amdgcn_mfma_f32_16x16x32_bf16(ah1, bl1, acc[nf], 0, 0, 0);
  }
  __shared__ float lds[64 * 66];          // [ac][o], stride 66 vs bank conflicts
#pragma unroll
  for (int nf = 0; nf < 4; ++nf)
#pragma unroll
    for (int r = 0; r < 4; ++r)
      lds[(w * 16 + 4 * (l >> 4) + r) * 66 + nf * 16 + (l & 15)] = acc[nf][r];
  __syncthreads();
  // pack: items a2(2) * nf(4) * l2(64) = 512, 2 iters
  short8v* dst = reinterpret_cast<short8v*>(Dp);
#pragma unroll
  for (int it = 0; it < 2; ++it) {
    int item = it * 256 + threadIdx.x;
    int a2 = item >> 8, nf = (item >> 6) & 3, l2 = item & 63;
    short8v hi, lo;
#pragma unroll
    for (int j = 0; j < 8; ++j) {
      float v = lds[(a2 * 32 + 8 * (l2 >> 4) + j) * 66 + nf * 16 + (l2 & 15)];
      unsigned short hh = f2bf(v);
      hi[j] = (short)hh; lo[j] = (short)f2bf(v - bf2f(hh));
    }
    int ks = st * 2 + a2;
    size_t base = ((((size_t)ij * 128 + ks) * 4 + nf) * 2) * 64 + l2;
    dst[base] = hi; dst[base + 64] = lo;
  }
}

// ---------------- GEMM-C: T4part[kc] = G23 @ D_ij (split-K x8, full o) ----------------

__global__ __launch_bounds__(256) void k_t4mm(const unsigned short* __restrict__ G23p,
                                              const unsigned short* __restrict__ Dp,
                                              float* __restrict__ T4part) {
  int bid = blockIdx.x;                   // 512: ij*8 + kc
  int ij = bid >> 3, kc = bid & 7;
  int w = threadIdx.x >> 6, l = threadIdx.x & 63;
  const short8v* ga = reinterpret_cast<const short8v*>(G23p);
  const short8v* gb = reinterpret_cast<const short8v*>(Dp);
  f32x4 acc[4];
#pragma unroll
  for (int nf = 0; nf < 4; ++nf) acc[nf] = (f32x4){0.f, 0.f, 0.f, 0.f};
#pragma unroll 2
  for (int ks = kc * 16; ks < kc * 16 + 16; ++ks) {
    size_t abase = (((size_t)ks * 4 + w) * 2) * 64 + l;
    short8v ah = ga[abase], al = ga[abase + 64];
#pragma unroll
    for (int nf = 0; nf < 4; ++nf) {
      size_t bbase = ((((size_t)ij * 128 + ks) * 4 + nf) * 2) * 64 + l;
      short8v bh = gb[bbase], bl = gb[bbase + 64];
      acc[nf] = __builtin_amdgcn_mfma_f32_16x16x32_bf16(ah, bh, acc[nf], 0, 0, 0);
      acc[nf] = __builtin_amdgcn_mfma_f32_16x16x32_bf16(al, bh, acc[nf], 0, 0, 0);
      acc[nf] = __builtin_amdgcn_mfma_f32_16x16x32_bf16(ah, bl, acc[nf], 0, 0, 0);
    }
  }
#pragma unroll
  for (int nf = 0; nf < 4; ++nf)
#pragma unroll
    for (int r = 0; r < 4; ++r) {
      int row = w * 16 + 4 * (l >> 4) + r;
      T4part[(((size_t)kc * 64 + ij) * 64 + row) * 64 + nf * 16 + (l & 15)] = acc[nf][r];
    }
}

// ---------------- reduce T4 partials + pack x-GEMM B-frag ----------------

__global__ __launch_bounds__(256) void k_pack2(const float* __restrict__ T4part,
                                               unsigned short* __restrict__ Bp) {
  int kb = blockIdx.x, tid = threadIdx.x; // 128 blocks, rows kb*32..+32
  __shared__ float ls[2048];
  f32x4 a0 = {0.f, 0.f, 0.f, 0.f}, a1 = a0;
#pragma unroll
  for (int kc = 0; kc < 8; ++kc) {
    const f32x4* src = reinterpret_cast<const f32x4*>(T4part + (size_t)kc * 262144 + kb * 2048);
    a0 += src[tid];
    a1 += src[256 + tid];
  }
  reinterpret_cast<f32x4*>(ls)[tid] = a0;
  reinterpret_cast<f32x4*>(ls)[256 + tid] = a1;
  __syncthreads();
  short8v* dst = reinterpret_cast<short8v*>(Bp);
  int nf = tid >> 6, l = tid & 63;
  short8v hi, lo;
#pragma unroll
  for (int j = 0; j < 8; ++j) {
    float v = ls[(8 * (l >> 4) + j) * 64 + nf * 16 + (l & 15)];
    unsigned short h = f2bf(v);
    hi[j] = (short)h; lo[j] = (short)f2bf(v - bf2f(h));
  }
  size_t base = (size_t)kb * 512 + (nf * 2) * 64 + l;
  dst[base] = hi; dst[base + 64] = lo;
}

// ---------------- Y = x @ T4 (split-K x16, trunc-split conversion) ----------------

__global__ __launch_bounds__(256) void k_ymm(const float* __restrict__ x,
                                             const unsigned short* __restrict__ Bp,
                                             float* __restrict__ Ypart) {
  int mt = blockIdx.x >> 4, kc = blockIdx.x & 15;
  int w = threadIdx.x >> 6, l = threadIdx.x & 63;
  int kg = l >> 4, lm = l & 15;
  const float4* xp = reinterpret_cast<const float4*>(
      x + (size_t)(mt * 64 + w * 16 + lm) * 4096 + kc * 256 + kg * 8);
  f32x4 acc0 = {0.f, 0.f, 0.f, 0.f}, acc1 = acc0, acc2 = acc0, acc3 = acc0;
#pragma unroll 1
  for (int s = 0; s < 8; ++s) {
    float4 xa = xp[s * 8], xb = xp[s * 8 + 1];
    float xs[8] = {xa.x, xa.y, xa.z, xa.w, xb.x, xb.y, xb.z, xb.w};
    short8v ah, al;
#pragma unroll
    for (int j = 0; j < 8; ++j) {         // trunc split: hi+lo error ~2^-16 rel
      unsigned u = __builtin_bit_cast(unsigned, xs[j]);
      unsigned short h = (unsigned short)(u >> 16);
      ah[j] = (short)h;
      float lo = xs[j] - bf2f(h);
      al[j] = (short)(__builtin_bit_cast(unsigned, lo) >> 16);
    }
    const short8v* bp = reinterpret_cast<const short8v*>(Bp + (size_t)(kc * 8 + s) * 4096) + l;
    short8v bh0 = bp[0],   bl0 = bp[64];
    short8v bh1 = bp[128], bl1 = bp[192];
    short8v bh2 = bp[256], bl2 = bp[320];
    short8v bh3 = bp[384], bl3 = bp[448];
    acc0 = __builtin_amdgcn_mfma_f32_16x16x32_bf16(ah, bh0, acc0, 0, 0, 0);
    acc1 = __builtin_amdgcn_mfma_f32_16x16x32_bf16(ah, bh1, acc1, 0, 0, 0);
    acc2 = __builtin_amdgcn_mfma_f32_16x16x32_bf16(ah, bh2, acc2, 0, 0, 0);
    acc3 = __builtin_amdgcn_mfma_f32_16x16x32_bf16(ah, bh3, acc3, 0, 0, 0);
    acc0 = __builtin_amdgcn_mfma_f32_16x16x32_bf16(al, bh0, acc0, 0, 0, 0);
    acc1 = __builtin_amdgcn_mfma_f32_16x16x32_bf16(al, bh1, acc1, 0, 0, 0);
    acc2 = __builtin_amdgcn_mfma_f32_16x16x32_bf16(al, bh2, acc2, 0, 0, 0);
    acc3 = __builtin_amdgcn_mfma_f32_16x16x32_bf16(al, bh3, acc3, 0, 0, 0);
    acc0 = __builtin_amdgcn_mfma_f32_16x16x32_bf16(ah, bl0, acc0, 0, 0, 0);
    acc1 = __builtin_amdgcn_mfma_f32_16x16x32_bf16(ah, bl1, acc1, 0, 0, 0);
    acc2 = __builtin_amdgcn_mfma_f32_16x16x32_bf16(ah, bl2, acc2, 0, 0, 0);
    acc3 = __builtin_amdgcn_mfma_f32_16x16x32_bf16(ah, bl3, acc3, 0, 0, 0);
  }
  float* yb = Ypart + (size_t)kc * 262144 + (size_t)(mt * 64 + w * 16) * 64;
#pragma unroll
  for (int r = 0; r < 4; ++r) {
    yb[(kg * 4 + r) * 64 + 0  + lm] = acc0[r];
    yb[(kg * 4 + r) * 64 + 16 + lm] = acc1[r];
    yb[(kg * 4 + r) * 64 + 32 + lm] = acc2[r];
    yb[(kg * 4 + r) * 64 + 48 + lm] = acc3[r];
  }
}

// ---------------- fused: reduce Ypart + out = Y @ OF + bias ----------------

__global__ __launch_bounds__(256) void k_out4(const float* __restrict__ Ypart,
                                              const unsigned short* __restrict__ OFp,
                                              const float* __restrict__ bias,
                                              float* __restrict__ out) {
  int mt16 = blockIdx.x;                  // 256 blocks, rows mt16*16..+16
  int tid = threadIdx.x;
  __shared__ float ls[1024];              // [16 rows][64 o]
  {
    f32x4 a = {0.f, 0.f, 0.f, 0.f};
#pragma unroll
    for (int kc = 0; kc < 16; ++kc)
      a += *reinterpret_cast<const f32x4*>(Ypart + (size_t)kc * 262144 + (size_t)mt16 * 1024 + tid * 4);
    *reinterpret_cast<f32x4*>(ls + tid * 4) = a;
  }
  __syncthreads();
  int w = tid >> 6, l = tid & 63;
  // A-frags (same 16-row m-frag per wave), trunc split
  short8v ya0, yl0, ya1, yl1;
#pragma unroll
  for (int j = 0; j < 8; ++j) {
    float v0 = ls[(l & 15) * 64 + 0  + 8 * (l >> 4) + j];
    float v1 = ls[(l & 15) * 64 + 32 + 8 * (l >> 4) + j];
    unsigned short h0 = (unsigned short)(__builtin_bit_cast(unsigned, v0) >> 16);
    unsigned short h1 = (unsigned short)(__builtin_bit_cast(unsigned, v1) >> 16);
    ya0[j] = (short)h0; yl0[j] = (short)(__builtin_bit_cast(unsigned, v0 - bf2f(h0)) >> 16);
    ya1[j] = (short)h1; yl1[j] = (short)(__builtin_bit_cast(unsigned, v1 - bf2f(h1)) >> 16);
  }
  const short8v* op = reinterpret_cast<const short8v*>(OFp);
#pragma unroll 4
  for (int nf = 0; nf < 16; ++nf) {
    int nfg = w * 16 + nf;
    size_t bb = (((size_t)nfg * 2) * 2) * 64 + l;
    short8v bh0 = op[bb], bl0 = op[bb + 64], bh1 = op[bb + 128], bl1 = op[bb + 192];
    f32x4 acc = {0.f, 0.f, 0.f, 0.f};
    acc = __builtin_amdgcn_mfma_f32_16x16x32_bf16(ya0, bh0, acc, 0, 0, 0);
    acc = __builtin_amdgcn_mfma_f32_16x16x32_bf16(yl0, bh0, acc, 0, 0, 0);
    acc = __builtin_amdgcn_mfma_f32_16x16x32_bf16(ya0, bl0, acc, 0, 0, 0);
    acc = __builtin_amdgcn_mfma_f32_16x16x32_bf16(ya1, bh1, acc, 0, 0, 0);
    acc = __builtin_amdgcn_mfma_f32_16x16x32_bf16(yl1, bh1, acc, 0, 0, 0);
    acc = __builtin_amdgcn_mfma_f32_16x16x32_bf16(ya1, bl1, acc, 0, 0, 0);
    float bv = bias[nfg * 16 + (l & 15)];
#pragma unroll
    for (int r = 0; r < 4; ++r)
      out[(size_t)(mt16 * 16 + 4 * (l >> 4) + r) * 1024 + nfg * 16 + (l & 15)] = acc[r] + bv;
  }
}

// ---------------- fallback (round-1 verified path) ----------------

__global__ __launch_bounds__(256) void k_t4(const float* __restrict__ A,
                                            const float* __restrict__ B,
                                            const float* __restrict__ core,
                                            float* __restrict__ T4) {
  int bid = blockIdx.x;
  int ij = bid >> 4, kl0 = (bid & 15) * 4;
  __shared__ float lA[4096];
  __shared__ float lS[4][4096];
  int tid = threadIdx.x;
#pragma unroll
  for (int r = 0; r < 4; ++r)
    reinterpret_cast<float4*>(lA)[r * 256 + tid] =
        reinterpret_cast<const float4*>(A + ij * 4096)[r * 256 + tid];
  __syncthreads();
  int pq0 = (tid >> 4) << 2;
  int st04 = tid & 15;
#pragma unroll 1
  for (int m = 0; m < 4; ++m) {
    const float4* Bp = reinterpret_cast<const float4*>(B + (kl0 + m) * 4096);
    float acc[4][4] = {{0.f}};
    for (int ac = 0; ac < 64; ++ac) {
      float4 av = reinterpret_cast<float4*>(lA)[ac * 16 + (pq0 >> 2)];
      float4 bv = Bp[ac * 16 + st04];
      float au[4] = {av.x, av.y, av.z, av.w};
      float bu[4] = {bv.x, bv.y, bv.z, bv.w};
#pragma unroll
      for (int u = 0; u < 4; ++u)
#pragma unroll
        for (int v = 0; v < 4; ++v)
          acc[u][v] = fmaf(au[u], bu[v], acc[u][v]);
    }
    float4* S4 = reinterpret_cast<float4*>(lS[m]);
#pragma unroll
    for (int u = 0; u < 4; ++u)
      S4[(pq0 + u) * 16 + st04] = make_float4(acc[u][0], acc[u][1], acc[u][2], acc[u][3]);
  }
  __syncthreads();
  int o44 = tid & 15, seg = tid >> 4;
  const float4* c4 = reinterpret_cast<const float4*>(core);
  float4 r0 = {0, 0, 0, 0}, r1 = r0, r2 = r0, r3 = r0;
  for (int n = 0; n < 256; ++n) {
    int midx = seg * 256 + n;
    float4 cv = c4[midx * 16 + o44];
    float s0 = lS[0][midx], s1 = lS[1][midx], s2 = lS[2][midx], s3 = lS[3][midx];
    r0.x = fmaf(s0, cv.x, r0.x); r0.y = fmaf(s0, cv.y, r0.y);
    r0.z = fmaf(s0, cv.z, r0.z); r0.w = fmaf(s0, cv.w, r0.w);
    r1.x = fmaf(s1, cv.x, r1.x); r1.y = fmaf(s1, cv.y, r1.y);
    r1.z = fmaf(s1, cv.z, r1.z); r1.w = fmaf(s1, cv.w, r1.w);
    r2.x = fmaf(s2, cv.x, r2.x); r2.y = fmaf(s2, cv.y, r2.y);
    r2.z = fmaf(s2, cv.z, r2.z); r2.w = fmaf(s2, cv.w, r2.w);
    r3.x = fmaf(s3, cv.x, r3.x); r3.y = fmaf(s3, cv.y, r3.y);
    r3.z = fmaf(s3, cv.z, r3.z); r3.w = fmaf(s3, cv.w, r3.w);
  }
  float4* red = reinterpret_cast<float4*>(lA);
  red[(seg * 4 + 0) * 16 + o44] = r0;
  red[(seg * 4 + 1) * 16 + o44] = r1;
  red[(seg * 4 + 2) * 16 + o44] = r2;
  red[(seg * 4 + 3) * 16 + o44] = r3;
  __syncthreads();
  int m2 = tid >> 6, o = tid & 63;
  float t = 0.f;
#pragma unroll
  for (int s2 = 0; s2 < 16; ++s2) t += lA[(s2 * 4 + m2) * 64 + o];
  T4[(ij * 64 + kl0 + m2) * 64 + o] = t;
}

__global__ __launch_bounds__(256) void k_y(const float* __restrict__ x,
                                           const float* __restrict__ T4,
                                           float* __restrict__ Y) {
  int b0 = blockIdx.x * 16;
  __shared__ float lx[1024];
  int tid = threadIdx.x;
  int o = tid & 63, rg = tid >> 6;
  float acc0 = 0.f, acc1 = 0.f, acc2 = 0.f, acc3 = 0.f;
  const float4* lx4 = reinterpret_cast<const float4*>(lx);
  for (int kc = 0; kc < 4096; kc += 64) {
    __syncthreads();
    reinterpret_cast<float4*>(lx)[tid] =
        *reinterpret_cast<const float4*>(x + (b0 + (tid >> 4)) * 4096 + kc + (tid & 15) * 4);
    __syncthreads();
#pragma unroll 4
    for (int kk = 0; kk < 64; kk += 4) {
      float c0 = T4[(kc + kk + 0) * 64 + o];
      float c1 = T4[(kc + kk + 1) * 64 + o];
      float c2 = T4[(kc + kk + 2) * 64 + o];
      float c3 = T4[(kc + kk + 3) * 64 + o];
      float4 xv;
      xv = lx4[(rg * 4 + 0) * 16 + (kk >> 2)];
      acc0 = fmaf(xv.x, c0, fmaf(xv.y, c1, fmaf(xv.z, c2, fmaf(xv.w, c3, acc0))));
      xv = lx4[(rg * 4 + 1) * 16 + (kk >> 2)];
      acc1 = fmaf(xv.x, c0, fmaf(xv.y, c1, fmaf(xv.z, c2, fmaf(xv.w, c3, acc1))));
      xv = lx4[(rg * 4 + 2) * 16 + (kk >> 2)];
      acc2 = fmaf(xv.x, c0, fmaf(xv.y, c1, fmaf(xv.z, c2, fmaf(xv.w, c3, acc2))));
      xv = lx4[(rg * 4 + 3) * 16 + (kk >> 2)];
      acc3 = fmaf(xv.x, c0, fmaf(xv.y, c1, fmaf(xv.z, c2, fmaf(xv.w, c3, acc3))));
    }
  }
  Y[(b0 + rg * 4 + 0) * 64 + o] = acc0;
  Y[(b0 + rg * 4 + 1) * 64 + o] = acc1;
  Y[(b0 + rg * 4 + 2) * 64 + o] = acc2;
  Y[(b0 + rg * 4 + 3) * 64 + o] = acc3;
}

__global__ __launch_bounds__(256) void k_out(const float* __restrict__ Y,
                                             const float* __restrict__ OF_,
                                             const float* __restrict__ bias,
                                             float* __restrict__ out) {
  int b0 = blockIdx.x * 16;
  int tid = threadIdx.x;
  __shared__ float lY[1024];
  reinterpret_cast<float4*>(lY)[tid] =
      *reinterpret_cast<const float4*>(Y + (b0 + (tid >> 4)) * 64 + (tid & 15) * 4);
  __syncthreads();
  float4 acc[16];
#pragma unroll
  for (int r = 0; r < 16; ++r) acc[r] = make_float4(0.f, 0.f, 0.f, 0.f);
  for (int oo = 0; oo < 64; ++oo) {
    float4 w = *reinterpret_cast<const float4*>(OF_ + oo * 1024 + tid * 4);
#pragma unroll
    for (int r = 0; r < 16; ++r) {
      float yv = lY[r * 64 + oo];
      acc[r].x = fmaf(yv, w.x, acc[r].x);
      acc[r].y = fmaf(yv, w.y, acc[r].y);
      acc[r].z = fmaf(yv, w.z, acc[r].z);
      acc[r].w = fmaf(yv, w.w, acc[r].w);
    }
  }
  float4 bv = *reinterpret_cast<const float4*>(bias + tid * 4);
#pragma unroll
  for (int r = 0; r < 16; ++r) {
    float4 v = acc[r];
    v.x += bv.x; v.y += bv.y; v.z += bv.z; v.w += bv.w;
    *reinterpret_cast<float4*>(out + (b0 + r) * 1024 + tid * 4) = v;
  }
}

// ---------------- host ----------------

extern "C" void kernel_launch(void* const* d_in, const int* in_sizes, int n_in,
                              void* d_out, int out_size, void* d_ws, size_t ws_size,
                              hipStream_t stream) {
  const float* x    = (const float*)d_in[0];
  const float* f0   = (const float*)d_in[1];
  const float* f1   = (const float*)d_in[2];
  const float* f2   = (const float*)d_in[3];
  const float* f3   = (const float*)d_in[4];
  const float* core = (const float*)d_in[5];
  const float* ofac = (const float*)d_in[6];
  const float* bias = (const float*)d_in[7];
  float* out = (float*)d_out;
  float* ws = (float*)d_ws;

  float* G01 = ws;
  float* G23 = ws + 262144;

  k_build<<<128, 256, 0, stream>>>(f0, f1, f2, f3, G01, G23);

  if (ws_size >= WS_NEED) {
    unsigned short* G01p = (unsigned short*)(ws + 524288);
    unsigned short* CP   = (unsigned short*)(ws + 786432);
    unsigned short* G23p = (unsigned short*)(ws + 1310720);
    unsigned short* Bp   = (unsigned short*)(ws + 1835008);
    unsigned short* OFp  = (unsigned short*)(ws + 2097152);
    float* T4part = ws + 2162688;         // 8 x 262144
    float* Ypart  = ws + 4259840;         // 16 x 262144
    unsigned short* Dp = (unsigned short*)(ws + 8454144);  // 67 MB

    k_packs<<<264, 256, 0, stream>>>(G01, G23, core, ofac, G01p, CP, G23p, OFp);
    k_dmat<<<4096, 256, 0, stream>>>(G01p, CP, Dp);
    k_t4mm<<<512, 256, 0, stream>>>(G23p, Dp, T4part);
    k_pack2<<<128, 256, 0, stream>>>(T4part, Bp);
    k_ymm<<<1024, 256, 0, stream>>>(x, Bp, Ypart);
    k_out4<<<256, 256, 0, stream>>>(Ypart, OFp, bias, out);
  } else {
    float* T4 = ws + 524288;
    float* Yb = ws + 786432;
    k_t4<<<1024, 256, 0, stream>>>(G01, G23, core, T4);
    k_y<<<256, 256, 0, stream>>>(x, T4, Yb);
    k_out<<<256, 256, 0, stream>>>(Yb, ofac, bias, out);
  }
}

// Round 8
// 168.035 us; speedup vs baseline: 2.3294x; 1.0637x over previous
//
#include <hip/hip_runtime.h>

// Tensor-ring layer v6 — fused T4 build (no Dp materialization), 6 launches.
// Fragment conventions (validated on-device rounds 3-6):
//   A[m][k]: lane l holds m = m0+(l&15), k = k0 + 8*(l>>4)+j   (short8v)
//   B[k][n]: lane l holds n = n0+(l&15), same k map
//   D[m][n]: lane l holds n = n0+(l&15), m = m0 + 4*(l>>4)+r   (f32x4)
// Pipeline:
//   k_build : G01[ij][ac*64+pq], G23[kl][ac*64+st]
//   k_packs : G01p (A-frag), CP (core B-frag), G23p (A-frag, k2=st*64+ac), OFp (B-frag)
//   k_t4f   : per (ij, st-chunk): E = G01_ij @ core_st (LDS), convert, T4 += G23_st @ E
//             -> T4part[stc]  (split x8, no atomics, no 67MB intermediate)
//   k_pack2 : reduce 8 partials -> Bp (x-GEMM B-frag)
//   k_ymm   : Ypart = x @ T4 (split-K x16, trunc-split conversions)
//   k_out4  : reduce Ypart + out = Y @ OF + bias (fused, MFMA)
// ws f32 offsets:
//   G01 0 | G23 262144 | G01p 524288 | CP 786432 | G23p 1048576 | Bp 1310720
//   | OFp 1572864 | T4part 1638400 (2097152) | Ypart 3735552 (4194304)
//   | end 7929856 (~31.7 MB)

#define WS_NEED ((size_t)7929856 * 4)

typedef __attribute__((ext_vector_type(8))) short short8v;
typedef __attribute__((ext_vector_type(4))) float f32x4;

__device__ inline unsigned short f2bf(float f) {       // RNE
  unsigned u = __builtin_bit_cast(unsigned, f);
  u += 0x7FFFu + ((u >> 16) & 1u);
  return (unsigned short)(u >> 16);
}
__device__ inline float bf2f(unsigned short h) {
  return __builtin_bit_cast(float, (unsigned)h << 16);
}

// ---------------- G01 / G23 build ----------------

__global__ __launch_bounds__(256) void k_build(const float* __restrict__ f0,
                                               const float* __restrict__ f1,
                                               const float* __restrict__ f2,
                                               const float* __restrict__ f3,
                                               float* __restrict__ G01,
                                               float* __restrict__ G23) {
  int bb = blockIdx.x, tid = threadIdx.x;
  __shared__ float lu[512], lv[512];
  bool is01 = bb < 64;
  int pairi = is01 ? bb : bb - 64;
  int iA = pairi >> 3, iB = pairi & 7;
  const float* fu = is01 ? f0 : f2;
  const float* fv = is01 ? f1 : f3;
  if (tid < 128)
    reinterpret_cast<float4*>(lu)[tid] = reinterpret_cast<const float4*>(fu + iA * 512)[tid];
  else
    reinterpret_cast<float4*>(lv)[tid - 128] = reinterpret_cast<const float4*>(fv + iB * 512)[tid - 128];
  __syncthreads();
  float* dst = is01 ? G01 : G23;
#pragma unroll
  for (int r = 0; r < 16; ++r) {
    int idx = r * 256 + tid;
    int uv = idx >> 6, pq = idx & 63;
    int a = uv >> 3, c = uv & 7, p = pq >> 3, q = pq & 7;
    float acc = 0.f;
    if (is01) {
#pragma unroll
      for (int b = 0; b < 8; ++b)
        acc = fmaf(lu[a * 64 + b * 8 + p], lv[b * 64 + c * 8 + q], acc);
    } else {
#pragma unroll
      for (int d = 0; d < 8; ++d)
        acc = fmaf(lu[c * 64 + d * 8 + p], lv[d * 64 + a * 8 + q], acc);
    }
    dst[pairi * 4096 + idx] = acc;
  }
}

// ---------------- pack G01p / CP / G23p / OFp ----------------

__global__ __launch_bounds__(256) void k_packs(const float* __restrict__ G01,
                                               const float* __restrict__ G23,
                                               const float* __restrict__ core,
                                               const float* __restrict__ OF_,
                                               unsigned short* __restrict__ G01p,
                                               unsigned short* __restrict__ CP,
                                               unsigned short* __restrict__ G23p,
                                               unsigned short* __restrict__ OFp) {
  int bb = blockIdx.x, tid = threadIdx.x;
  __shared__ float ls[8192];
  if (bb < 64) {                          // G01p: A-frag, ij = bb
    int ij = bb;
#pragma unroll
    for (int r = 0; r < 4; ++r)
      reinterpret_cast<float4*>(ls)[r * 256 + tid] =
          reinterpret_cast<const float4*>(G01 + ij * 4096)[r * 256 + tid];
    __syncthreads();
    short8v* dst = reinterpret_cast<short8v*>(G01p);
#pragma unroll
    for (int it = 0; it < 2; ++it) {
      int item = it * 256 + tid;          // ks(2)*mf(4)*l(64)
      int ks = item >> 8, mf = (item >> 6) & 3, l = item & 63;
      short8v hi, lo;
#pragma unroll
      for (int j = 0; j < 8; ++j) {
        float v = ls[(mf * 16 + (l & 15)) * 64 + ks * 32 + 8 * (l >> 4) + j];
        unsigned short h = f2bf(v);
        hi[j] = (short)h; lo[j] = (short)f2bf(v - bf2f(h));
      }
      size_t base = ((((size_t)ij * 2 + ks) * 4 + mf) * 2) * 64 + l;
      dst[base] = hi; dst[base + 64] = lo;
    }
  } else if (bb < 128) {                  // CP: B-frag, st = bb-64
    int st = bb - 64;
#pragma unroll
    for (int r = 0; r < 4; ++r) {
      int f4 = r * 256 + tid;             // pq = f4>>4, o4 = f4&15
      reinterpret_cast<float4*>(ls)[f4] =
          reinterpret_cast<const float4*>(core)[(f4 >> 4) * 1024 + st * 16 + (f4 & 15)];
    }
    __syncthreads();
    short8v* dst = reinterpret_cast<short8v*>(CP);
#pragma unroll
    for (int it = 0; it < 2; ++it) {
      int item = it * 256 + tid;          // ks(2)*nf(4)*l(64)
      int ks = item >> 8, nf = (item >> 6) & 3, l = item & 63;
      short8v hi, lo;
#pragma unroll
      for (int j = 0; j < 8; ++j) {
        float v = ls[(ks * 32 + 8 * (l >> 4) + j) * 64 + nf * 16 + (l & 15)];
        unsigned short h = f2bf(v);
        hi[j] = (short)h; lo[j] = (short)f2bf(v - bf2f(h));
      }
      size_t base = ((((size_t)st * 2 + ks) * 4 + nf) * 2) * 64 + l;
      dst[base] = hi; dst[base + 64] = lo;
    }
  } else if (bb < 256) {                  // G23p: A-frag, ks = bb-128
    int ks = bb - 128;                    // k2 = st*64+ac ; st = ks>>1, ac = (ks&1)*32+koff
    int st = ks >> 1, acb = (ks & 1) * 32;
#pragma unroll
    for (int r = 0; r < 8; ++r) {
      int idx = r * 256 + tid;            // kl = idx>>5, a = idx&31
      ls[idx] = G23[(idx >> 5) * 4096 + (acb + (idx & 31)) * 64 + st];
    }
    __syncthreads();
    short8v* dst = reinterpret_cast<short8v*>(G23p);
    int mf = tid >> 6, l = tid & 63;
    short8v hi, lo;
#pragma unroll
    for (int j = 0; j < 8; ++j) {
      float v = ls[(mf * 16 + (l & 15)) * 32 + 8 * (l >> 4) + j];
      unsigned short h = f2bf(v);
      hi[j] = (short)h; lo[j] = (short)f2bf(v - bf2f(h));
    }
    size_t base = (((size_t)ks * 4 + mf) * 2) * 64 + l;
    dst[base] = hi; dst[base + 64] = lo;
  } else {                                // OFp: 8 blocks, f-group g = bb-256
    int g = bb - 256;
#pragma unroll
    for (int it = 0; it < 8; ++it) {
      int f4 = it * 256 + tid;            // o = f4>>5, c4 = f4&31
      reinterpret_cast<float4*>(ls)[f4] =
          reinterpret_cast<const float4*>(OF_)[(f4 >> 5) * 256 + g * 32 + (f4 & 31)];
    }
    __syncthreads();
    short8v* dst = reinterpret_cast<short8v*>(OFp);
#pragma unroll
    for (int it = 0; it < 4; ++it) {
      int item = it * 256 + tid;          // nfl(8)*ks(2)*l(64)
      int nfl = item >> 7, ks = (item >> 6) & 1, l = item & 63;
      short8v hi, lo;
#pragma unroll
      for (int j = 0; j < 8; ++j) {
        float v = ls[(ks * 32 + 8 * (l >> 4) + j) * 128 + nfl * 16 + (l & 15)];
        unsigned short h = f2bf(v);
        hi[j] = (short)h; lo[j] = (short)f2bf(v - bf2f(h));
      }
      int nfg = g * 8 + nfl;
      size_t base = (((size_t)nfg * 2 + ks) * 2) * 64 + l;
      dst[base] = hi; dst[base + 64] = lo;
    }
  }
}

// ---------------- fused T4 build: E = G01_ij @ core_st ; T4 += G23_st @ E ----------------
// 512 blocks = ij(64) x stc(8); each handles 8 st. All operands L2-resident packs.

__global__ __launch_bounds__(256) void k_t4f(const unsigned short* __restrict__ G01p,
                                             const unsigned short* __restrict__ CP,
                                             const unsigned short* __restrict__ G23p,
                                             float* __restrict__ T4part) {
  int bid = blockIdx.x;
  int ij = bid >> 3, stc = bid & 7;
  int tid = threadIdx.x;
  int w = tid >> 6, l = tid & 63;
  const short8v* gp = reinterpret_cast<const short8v*>(G01p);
  const short8v* cp = reinterpret_cast<const short8v*>(CP);
  const short8v* ga = reinterpret_cast<const short8v*>(G23p);
  // G01 A-frags for this wave's ac-tile (mf = w), st-invariant
  short8v a0h = gp[((((size_t)ij * 2 + 0) * 4 + w) * 2) * 64 + l];
  short8v a0l = gp[((((size_t)ij * 2 + 0) * 4 + w) * 2) * 64 + 64 + l];
  short8v a1h = gp[((((size_t)ij * 2 + 1) * 4 + w) * 2) * 64 + l];
  short8v a1l = gp[((((size_t)ij * 2 + 1) * 4 + w) * 2) * 64 + 64 + l];
  __shared__ float Ef[64 * 66];           // E staging, stride 66 vs bank conflicts
  __shared__ short EB[8192];              // E as bf16 B-frags: [kch2][nf4][hilo2][64l][8]
  short8v* EBv = reinterpret_cast<short8v*>(EB);
  f32x4 accT[4];
#pragma unroll
  for (int nf = 0; nf < 4; ++nf) accT[nf] = (f32x4){0.f, 0.f, 0.f, 0.f};

#pragma unroll 1
  for (int si = 0; si < 8; ++si) {
    int st = stc * 8 + si;
    // E-GEMM: wave w computes E rows w*16..+16, all 64 o
    f32x4 accE[4];
#pragma unroll
    for (int nf = 0; nf < 4; ++nf) accE[nf] = (f32x4){0.f, 0.f, 0.f, 0.f};
#pragma unroll
    for (int nf = 0; nf < 4; ++nf) {
      short8v bh0 = cp[((((size_t)st * 2 + 0) * 4 + nf) * 2) * 64 + l];
      short8v bl0 = cp[((((size_t)st * 2 + 0) * 4 + nf) * 2) * 64 + 64 + l];
      short8v bh1 = cp[((((size_t)st * 2 + 1) * 4 + nf) * 2) * 64 + l];
      short8v bl1 = cp[((((size_t)st * 2 + 1) * 4 + nf) * 2) * 64 + 64 + l];
      accE[nf] = __builtin_amdgcn_mfma_f32_16x16x32_bf16(a0h, bh0, accE[nf], 0, 0, 0);
      accE[nf] = __builtin_amdgcn_mfma_f32_16x16x32_bf16(a0l, bh0, accE[nf], 0, 0, 0);
      accE[nf] = __builtin_amdgcn_mfma_f32_16x16x32_bf16(a0h, bl0, accE[nf], 0, 0, 0);
      accE[nf] = __builtin_amdgcn_mfma_f32_16x16x32_bf16(a1h, bh1, accE[nf], 0, 0, 0);
      accE[nf] = __builtin_amdgcn_mfma_f32_16x16x32_bf16(a1l, bh1, accE[nf], 0, 0, 0);
      accE[nf] = __builtin_amdgcn_mfma_f32_16x16x32_bf16(a1h, bl1, accE[nf], 0, 0, 0);
    }
    // stage E (D-layout: row = w*16 + 4*(l>>4)+r, col = nf*16 + (l&15))
#pragma unroll
    for (int nf = 0; nf < 4; ++nf)
#pragma unroll
      for (int r = 0; r < 4; ++r)
        Ef[(w * 16 + 4 * (l >> 4) + r) * 66 + nf * 16 + (l & 15)] = accE[nf][r];
    __syncthreads();
    // convert E -> bf16 hi/lo B-frags (512 items, 2/thread)
#pragma unroll
    for (int it = 0; it < 2; ++it) {
      int item = it * 256 + tid;          // kch(2)*nf(4)*l2(64)
      int kch = item >> 8, nf = (item >> 6) & 3, l2 = item & 63;
      short8v hi, lo;
#pragma unroll
      for (int j = 0; j < 8; ++j) {
        float v = Ef[(kch * 32 + 8 * (l2 >> 4) + j) * 66 + nf * 16 + (l2 & 15)];
        unsigned short hh = f2bf(v);
        hi[j] = (short)hh; lo[j] = (short)f2bf(v - bf2f(hh));
      }
      EBv[((kch * 4 + nf) * 2 + 0) * 64 + l2] = hi;
      EBv[((kch * 4 + nf) * 2 + 1) * 64 + l2] = lo;
    }
    __syncthreads();
    // T4-GEMM: wave w computes kl rows w*16..+16, accumulate over this st
#pragma unroll
    for (int kch = 0; kch < 2; ++kch) {
      size_t abase = ((((size_t)(st * 2 + kch)) * 4 + w) * 2) * 64 + l;
      short8v ah = ga[abase], al = ga[abase + 64];
#pragma unroll
      for (int nf = 0; nf < 4; ++nf) {
        short8v bh = EBv[((kch * 4 + nf) * 2 + 0) * 64 + l];
        short8v bl = EBv[((kch * 4 + nf) * 2 + 1) * 64 + l];
        accT[nf] = __builtin_amdgcn_mfma_f32_16x16x32_bf16(ah, bh, accT[nf], 0, 0, 0);
        accT[nf] = __builtin_amdgcn_mfma_f32_16x16x32_bf16(al, bh, accT[nf], 0, 0, 0);
        accT[nf] = __builtin_amdgcn_mfma_f32_16x16x32_bf16(ah, bl, accT[nf], 0, 0, 0);
      }
    }
  }
#pragma unroll
  for (int nf = 0; nf < 4; ++nf)
#pragma unroll
    for (int r = 0; r < 4; ++r) {
      int row = w * 16 + 4 * (l >> 4) + r;
      T4part[(((size_t)stc * 64 + ij) * 64 + row) * 64 + nf * 16 + (l & 15)] = accT[nf][r];
    }
}

// ---------------- reduce T4 partials + pack x-GEMM B-frag ----------------

__global__ __launch_bounds__(256) void k_pack2(const float* __restrict__ T4part,
                                               unsigned short* __restrict__ Bp) {
  int kb = blockIdx.x, tid = threadIdx.x; // 128 blocks, rows kb*32..+32
  __shared__ float ls[2048];
  f32x4 a0 = {0.f, 0.f, 0.f, 0.f}, a1 = a0;
#pragma unroll
  for (int kc = 0; kc < 8; ++kc) {
    const f32x4* src = reinterpret_cast<const f32x4*>(T4part + (size_t)kc * 262144 + kb * 2048);
    a0 += src[tid];
    a1 += src[256 + tid];
  }
  reinterpret_cast<f32x4*>(ls)[tid] = a0;
  reinterpret_cast<f32x4*>(ls)[256 + tid] = a1;
  __syncthreads();
  short8v* dst = reinterpret_cast<short8v*>(Bp);
  int nf = tid >> 6, l = tid & 63;
  short8v hi, lo;
#pragma unroll
  for (int j = 0; j < 8; ++j) {
    float v = ls[(8 * (l >> 4) + j) * 64 + nf * 16 + (l & 15)];
    unsigned short h = f2bf(v);
    hi[j] = (short)h; lo[j] = (short)f2bf(v - bf2f(h));
  }
  size_t base = (size_t)kb * 512 + (nf * 2) * 64 + l;
  dst[base] = hi; dst[base + 64] = lo;
}

// ---------------- Y = x @ T4 (split-K x16, trunc-split conversion) ----------------

__global__ __launch_bounds__(256) void k_ymm(const float* __restrict__ x,
                                             const unsigned short* __restrict__ Bp,
                                             float* __restrict__ Ypart) {
  int mt = blockIdx.x >> 4, kc = blockIdx.x & 15;
  int w = threadIdx.x >> 6, l = threadIdx.x & 63;
  int kg = l >> 4, lm = l & 15;
  const float4* xp = reinterpret_cast<const float4*>(
      x + (size_t)(mt * 64 + w * 16 + lm) * 4096 + kc * 256 + kg * 8);
  f32x4 acc0 = {0.f, 0.f, 0.f, 0.f}, acc1 = acc0, acc2 = acc0, acc3 = acc0;
#pragma unroll 1
  for (int s = 0; s < 8; ++s) {
    float4 xa = xp[s * 8], xb = xp[s * 8 + 1];
    float xs[8] = {xa.x, xa.y, xa.z, xa.w, xb.x, xb.y, xb.z, xb.w};
    short8v ah, al;
#pragma unroll
    for (int j = 0; j < 8; ++j) {         // trunc split
      unsigned u = __builtin_bit_cast(unsigned, xs[j]);
      unsigned short h = (unsigned short)(u >> 16);
      ah[j] = (short)h;
      float lo = xs[j] - bf2f(h);
      al[j] = (short)(__builtin_bit_cast(unsigned, lo) >> 16);
    }
    const short8v* bp = reinterpret_cast<const short8v*>(Bp + (size_t)(kc * 8 + s) * 4096) + l;
    short8v bh0 = bp[0],   bl0 = bp[64];
    short8v bh1 = bp[128], bl1 = bp[192];
    short8v bh2 = bp[256], bl2 = bp[320];
    short8v bh3 = bp[384], bl3 = bp[448];
    acc0 = __builtin_amdgcn_mfma_f32_16x16x32_bf16(ah, bh0, acc0, 0, 0, 0);
    acc1 = __builtin_amdgcn_mfma_f32_16x16x32_bf16(ah, bh1, acc1, 0, 0, 0);
    acc2 = __builtin_amdgcn_mfma_f32_16x16x32_bf16(ah, bh2, acc2, 0, 0, 0);
    acc3 = __builtin_amdgcn_mfma_f32_16x16x32_bf16(ah, bh3, acc3, 0, 0, 0);
    acc0 = __builtin_amdgcn_mfma_f32_16x16x32_bf16(al, bh0, acc0, 0, 0, 0);
    acc1 = __builtin_amdgcn_mfma_f32_16x16x32_bf16(al, bh1, acc1, 0, 0, 0);
    acc2 = __builtin_amdgcn_mfma_f32_16x16x32_bf16(al, bh2, acc2, 0, 0, 0);
    acc3 = __builtin_amdgcn_mfma_f32_16x16x32_bf16(al, bh3, acc3, 0, 0, 0);
    acc0 = __builtin_amdgcn_mfma_f32_16x16x32_bf16(ah, bl0, acc0, 0, 0, 0);
    acc1 = __builtin_amdgcn_mfma_f32_16x16x32_bf16(ah, bl1, acc1, 0, 0, 0);
    acc2 = __builtin_amdgcn_mfma_f32_16x16x32_bf16(ah, bl2, acc2, 0, 0, 0);
    acc3 = __builtin_amdgcn_mfma_f32_16x16x32_bf16(ah, bl3, acc3, 0, 0, 0);
  }
  float* yb = Ypart + (size_t)kc * 262144 + (size_t)(mt * 64 + w * 16) * 64;
#pragma unroll
  for (int r = 0; r < 4; ++r) {
    yb[(kg * 4 + r) * 64 + 0  + lm] = acc0[r];
    yb[(kg * 4 + r) * 64 + 16 + lm] = acc1[r];
    yb[(kg * 4 + r) * 64 + 32 + lm] = acc2[r];
    yb[(kg * 4 + r) * 64 + 48 + lm] = acc3[r];
  }
}

// ---------------- fused: reduce Ypart + out = Y @ OF + bias ----------------

__global__ __launch_bounds__(256) void k_out4(const float* __restrict__ Ypart,
                                              const unsigned short* __restrict__ OFp,
                                              const float* __restrict__ bias,
                                              float* __restrict__ out) {
  int mt16 = blockIdx.x;                  // 256 blocks, rows mt16*16..+16
  int tid = threadIdx.x;
  __shared__ float ls[1024];              // [16 rows][64 o]
  {
    f32x4 a = {0.f, 0.f, 0.f, 0.f};
#pragma unroll
    for (int kc = 0; kc < 16; ++kc)
      a += *reinterpret_cast<const f32x4*>(Ypart + (size_t)kc * 262144 + (size_t)mt16 * 1024 + tid * 4);
    *reinterpret_cast<f32x4*>(ls + tid * 4) = a;
  }
  __syncthreads();
  int w = tid >> 6, l = tid & 63;
  short8v ya0, yl0, ya1, yl1;
#pragma unroll
  for (int j = 0; j < 8; ++j) {
    float v0 = ls[(l & 15) * 64 + 0  + 8 * (l >> 4) + j];
    float v1 = ls[(l & 15) * 64 + 32 + 8 * (l >> 4) + j];
    unsigned short h0 = (unsigned short)(__builtin_bit_cast(unsigned, v0) >> 16);
    unsigned short h1 = (unsigned short)(__builtin_bit_cast(unsigned, v1) >> 16);
    ya0[j] = (short)h0; yl0[j] = (short)(__builtin_bit_cast(unsigned, v0 - bf2f(h0)) >> 16);
    ya1[j] = (short)h1; yl1[j] = (short)(__builtin_bit_cast(unsigned, v1 - bf2f(h1)) >> 16);
  }
  const short8v* op = reinterpret_cast<const short8v*>(OFp);
#pragma unroll 4
  for (int nf = 0; nf < 16; ++nf) {
    int nfg = w * 16 + nf;
    size_t bb = (((size_t)nfg * 2) * 2) * 64 + l;
    short8v bh0 = op[bb], bl0 = op[bb + 64], bh1 = op[bb + 128], bl1 = op[bb + 192];
    f32x4 acc = {0.f, 0.f, 0.f, 0.f};
    acc = __builtin_amdgcn_mfma_f32_16x16x32_bf16(ya0, bh0, acc, 0, 0, 0);
    acc = __builtin_amdgcn_mfma_f32_16x16x32_bf16(yl0, bh0, acc, 0, 0, 0);
    acc = __builtin_amdgcn_mfma_f32_16x16x32_bf16(ya0, bl0, acc, 0, 0, 0);
    acc = __builtin_amdgcn_mfma_f32_16x16x32_bf16(ya1, bh1, acc, 0, 0, 0);
    acc = __builtin_amdgcn_mfma_f32_16x16x32_bf16(yl1, bh1, acc, 0, 0, 0);
    acc = __builtin_amdgcn_mfma_f32_16x16x32_bf16(ya1, bl1, acc, 0, 0, 0);
    float bv = bias[nfg * 16 + (l & 15)];
#pragma unroll
    for (int r = 0; r < 4; ++r)
      out[(size_t)(mt16 * 16 + 4 * (l >> 4) + r) * 1024 + nfg * 16 + (l & 15)] = acc[r] + bv;
  }
}

// ---------------- fallback (round-1 verified path) ----------------

__global__ __launch_bounds__(256) void k_t4(const float* __restrict__ A,
                                            const float* __restrict__ B,
                                            const float* __restrict__ core,
                                            float* __restrict__ T4) {
  int bid = blockIdx.x;
  int ij = bid >> 4, kl0 = (bid & 15) * 4;
  __shared__ float lA[4096];
  __shared__ float lS[4][4096];
  int tid = threadIdx.x;
#pragma unroll
  for (int r = 0; r < 4; ++r)
    reinterpret_cast<float4*>(lA)[r * 256 + tid] =
        reinterpret_cast<const float4*>(A + ij * 4096)[r * 256 + tid];
  __syncthreads();
  int pq0 = (tid >> 4) << 2;
  int st04 = tid & 15;
#pragma unroll 1
  for (int m = 0; m < 4; ++m) {
    const float4* Bp = reinterpret_cast<const float4*>(B + (kl0 + m) * 4096);
    float acc[4][4] = {{0.f}};
    for (int ac = 0; ac < 64; ++ac) {
      float4 av = reinterpret_cast<float4*>(lA)[ac * 16 + (pq0 >> 2)];
      float4 bv = Bp[ac * 16 + st04];
      float au[4] = {av.x, av.y, av.z, av.w};
      float bu[4] = {bv.x, bv.y, bv.z, bv.w};
#pragma unroll
      for (int u = 0; u < 4; ++u)
#pragma unroll
        for (int v = 0; v < 4; ++v)
          acc[u][v] = fmaf(au[u], bu[v], acc[u][v]);
    }
    float4* S4 = reinterpret_cast<float4*>(lS[m]);
#pragma unroll
    for (int u = 0; u < 4; ++u)
      S4[(pq0 + u) * 16 + st04] = make_float4(acc[u][0], acc[u][1], acc[u][2], acc[u][3]);
  }
  __syncthreads();
  int o44 = tid & 15, seg = tid >> 4;
  const float4* c4 = reinterpret_cast<const float4*>(core);
  float4 r0 = {0, 0, 0, 0}, r1 = r0, r2 = r0, r3 = r0;
  for (int n = 0; n < 256; ++n) {
    int midx = seg * 256 + n;
    float4 cv = c4[midx * 16 + o44];
    float s0 = lS[0][midx], s1 = lS[1][midx], s2 = lS[2][midx], s3 = lS[3][midx];
    r0.x = fmaf(s0, cv.x, r0.x); r0.y = fmaf(s0, cv.y, r0.y);
    r0.z = fmaf(s0, cv.z, r0.z); r0.w = fmaf(s0, cv.w, r0.w);
    r1.x = fmaf(s1, cv.x, r1.x); r1.y = fmaf(s1, cv.y, r1.y);
    r1.z = fmaf(s1, cv.z, r1.z); r1.w = fmaf(s1, cv.w, r1.w);
    r2.x = fmaf(s2, cv.x, r2.x); r2.y = fmaf(s2, cv.y, r2.y);
    r2.z = fmaf(s2, cv.z, r2.z); r2.w = fmaf(s2, cv.w, r2.w);
    r3.x = fmaf(s3, cv.x, r3.x); r3.y = fmaf(s3, cv.y, r3.y);
    r3.z = fmaf(s3, cv.z, r3.z); r3.w = fmaf(s3, cv.w, r3.w);
  }
  float4* red = reinterpret_cast<float4*>(lA);
  red[(seg * 4 + 0) * 16 + o44] = r0;
  red[(seg * 4 + 1) * 16 + o44] = r1;
  red[(seg * 4 + 2) * 16 + o44] = r2;
  red[(seg * 4 + 3) * 16 + o44] = r3;
  __syncthreads();
  int m2 = tid >> 6, o = tid & 63;
  float t = 0.f;
#pragma unroll
  for (int s2 = 0; s2 < 16; ++s2) t += lA[(s2 * 4 + m2) * 64 + o];
  T4[(ij * 64 + kl0 + m2) * 64 + o] = t;
}

__global__ __launch_bounds__(256) void k_y(const float* __restrict__ x,
                                           const float* __restrict__ T4,
                                           float* __restrict__ Y) {
  int b0 = blockIdx.x * 16;
  __shared__ float lx[1024];
  int tid = threadIdx.x;
  int o = tid & 63, rg = tid >> 6;
  float acc0 = 0.f, acc1 = 0.f, acc2 = 0.f, acc3 = 0.f;
  const float4* lx4 = reinterpret_cast<const float4*>(lx);
  for (int kc = 0; kc < 4096; kc += 64) {
    __syncthreads();
    reinterpret_cast<float4*>(lx)[tid] =
        *reinterpret_cast<const float4*>(x + (b0 + (tid >> 4)) * 4096 + kc + (tid & 15) * 4);
    __syncthreads();
#pragma unroll 4
    for (int kk = 0; kk < 64; kk += 4) {
      float c0 = T4[(kc + kk + 0) * 64 + o];
      float c1 = T4[(kc + kk + 1) * 64 + o];
      float c2 = T4[(kc + kk + 2) * 64 + o];
      float c3 = T4[(kc + kk + 3) * 64 + o];
      float4 xv;
      xv = lx4[(rg * 4 + 0) * 16 + (kk >> 2)];
      acc0 = fmaf(xv.x, c0, fmaf(xv.y, c1, fmaf(xv.z, c2, fmaf(xv.w, c3, acc0))));
      xv = lx4[(rg * 4 + 1) * 16 + (kk >> 2)];
      acc1 = fmaf(xv.x, c0, fmaf(xv.y, c1, fmaf(xv.z, c2, fmaf(xv.w, c3, acc1))));
      xv = lx4[(rg * 4 + 2) * 16 + (kk >> 2)];
      acc2 = fmaf(xv.x, c0, fmaf(xv.y, c1, fmaf(xv.z, c2, fmaf(xv.w, c3, acc2))));
      xv = lx4[(rg * 4 + 3) * 16 + (kk >> 2)];
      acc3 = fmaf(xv.x, c0, fmaf(xv.y, c1, fmaf(xv.z, c2, fmaf(xv.w, c3, acc3))));
    }
  }
  Y[(b0 + rg * 4 + 0) * 64 + o] = acc0;
  Y[(b0 + rg * 4 + 1) * 64 + o] = acc1;
  Y[(b0 + rg * 4 + 2) * 64 + o] = acc2;
  Y[(b0 + rg * 4 + 3) * 64 + o] = acc3;
}

__global__ __launch_bounds__(256) void k_out(const float* __restrict__ Y,
                                             const float* __restrict__ OF_,
                                             const float* __restrict__ bias,
                                             float* __restrict__ out) {
  int b0 = blockIdx.x * 16;
  int tid = threadIdx.x;
  __shared__ float lY[1024];
  reinterpret_cast<float4*>(lY)[tid] =
      *reinterpret_cast<const float4*>(Y + (b0 + (tid >> 4)) * 64 + (tid & 15) * 4);
  __syncthreads();
  float4 acc[16];
#pragma unroll
  for (int r = 0; r < 16; ++r) acc[r] = make_float4(0.f, 0.f, 0.f, 0.f);
  for (int oo = 0; oo < 64; ++oo) {
    float4 w = *reinterpret_cast<const float4*>(OF_ + oo * 1024 + tid * 4);
#pragma unroll
    for (int r = 0; r < 16; ++r) {
      float yv = lY[r * 64 + oo];
      acc[r].x = fmaf(yv, w.x, acc[r].x);
      acc[r].y = fmaf(yv, w.y, acc[r].y);
      acc[r].z = fmaf(yv, w.z, acc[r].z);
      acc[r].w = fmaf(yv, w.w, acc[r].w);
    }
  }
  float4 bv = *reinterpret_cast<const float4*>(bias + tid * 4);
#pragma unroll
  for (int r = 0; r < 16; ++r) {
    float4 v = acc[r];
    v.x += bv.x; v.y += bv.y; v.z += bv.z; v.w += bv.w;
    *reinterpret_cast<float4*>(out + (b0 + r) * 1024 + tid * 4) = v;
  }
}

// ---------------- host ----------------

extern "C" void kernel_launch(void* const* d_in, const int* in_sizes, int n_in,
                              void* d_out, int out_size, void* d_ws, size_t ws_size,
                              hipStream_t stream) {
  const float* x    = (const float*)d_in[0];
  const float* f0   = (const float*)d_in[1];
  const float* f1   = (const float*)d_in[2];
  const float* f2   = (const float*)d_in[3];
  const float* f3   = (const float*)d_in[4];
  const float* core = (const float*)d_in[5];
  const float* ofac = (const float*)d_in[6];
  const float* bias = (const float*)d_in[7];
  float* out = (float*)d_out;
  float* ws = (float*)d_ws;

  float* G01 = ws;
  float* G23 = ws + 262144;

  k_build<<<128, 256, 0, stream>>>(f0, f1, f2, f3, G01, G23);

  if (ws_size >= WS_NEED) {
    unsigned short* G01p = (unsigned short*)(ws + 524288);
    unsigned short* CP   = (unsigned short*)(ws + 786432);
    unsigned short* G23p = (unsigned short*)(ws + 1048576);
    unsigned short* Bp   = (unsigned short*)(ws + 1310720);
    unsigned short* OFp  = (unsigned short*)(ws + 1572864);
    float* T4part = ws + 1638400;         // 8 x 262144
    float* Ypart  = ws + 3735552;         // 16 x 262144

    k_packs<<<264, 256, 0, stream>>>(G01, G23, core, ofac, G01p, CP, G23p, OFp);
    k_t4f<<<512, 256, 0, stream>>>(G01p, CP, G23p, T4part);
    k_pack2<<<128, 256, 0, stream>>>(T4part, Bp);
    k_ymm<<<1024, 256, 0, stream>>>(x, Bp, Ypart);
    k_out4<<<256, 256, 0, stream>>>(Ypart, OFp, bias, out);
  } else {
    float* T4 = ws + 524288;
    float* Yb = ws + 786432;
    k_t4<<<1024, 256, 0, stream>>>(G01, G23, core, T4);
    k_y<<<256, 256, 0, stream>>>(x, T4, Yb);
    k_out<<<256, 256, 0, stream>>>(Yb, ofac, bias, out);
  }
}

// Round 9
// 167.552 us; speedup vs baseline: 2.3361x; 1.0029x over previous
//
#include <hip/hip_runtime.h>

// Tensor-ring layer v7 — 5 launches: pack kernels compute G01/G23 inline from the
// tiny factors (k_build folded in); k_ymm gets explicit next-iter x prefetch.
// Fragment conventions (validated on-device rounds 3-8):
//   A[m][k]: lane l holds m = m0+(l&15), k = k0 + 8*(l>>4)+j   (short8v)
//   B[k][n]: lane l holds n = n0+(l&15), same k map
//   D[m][n]: lane l holds n = n0+(l&15), m = m0 + 4*(l>>4)+r   (f32x4)
// Pipeline:
//   k_packs : G01p (A-frag), CP (core B-frag), G23p (A-frag, k2=st*64+ac), OFp (B-frag)
//             — G01/G23 values recomputed in-block from f0..f3 (2KB each)
//   k_t4f   : per (ij, st-chunk): E = G01_ij @ core_st (LDS), convert, T4 += G23_st @ E
//   k_pack2 : reduce 8 partials -> Bp (x-GEMM B-frag)
//   k_ymm   : Ypart = x @ T4 (split-K x16, trunc-split, x prefetch)
//   k_out4  : reduce Ypart + out = Y @ OF + bias (fused, MFMA)
// ws f32 offsets (fast path):
//   G01p 524288 | CP 786432 | G23p 1048576 | Bp 1310720 | OFp 1572864
//   | T4part 1638400 (2097152) | Ypart 3735552 (4194304) | end 7929856 (~31.7MB)

#define WS_NEED ((size_t)7929856 * 4)

typedef __attribute__((ext_vector_type(8))) short short8v;
typedef __attribute__((ext_vector_type(4))) float f32x4;

__device__ inline unsigned short f2bf(float f) {       // RNE
  unsigned u = __builtin_bit_cast(unsigned, f);
  u += 0x7FFFu + ((u >> 16) & 1u);
  return (unsigned short)(u >> 16);
}
__device__ inline float bf2f(unsigned short h) {
  return __builtin_bit_cast(float, (unsigned)h << 16);
}

// ---------------- pack G01p / CP / G23p / OFp (G computed inline) ----------------

__global__ __launch_bounds__(256) void k_packs(const float* __restrict__ f0,
                                               const float* __restrict__ f1,
                                               const float* __restrict__ f2,
                                               const float* __restrict__ f3,
                                               const float* __restrict__ core,
                                               const float* __restrict__ OF_,
                                               unsigned short* __restrict__ G01p,
                                               unsigned short* __restrict__ CP,
                                               unsigned short* __restrict__ G23p,
                                               unsigned short* __restrict__ OFp) {
  int bb = blockIdx.x, tid = threadIdx.x;
  __shared__ float sh[10240];
  if (bb < 64) {                          // G01p: A-frag, ij = bb (compute G01[ij] inline)
    int ij = bb, i = ij >> 3, j = ij & 7;
    float* lu = sh;                       // f0[i] 512
    float* lv = sh + 512;                 // f1[j] 512
    float* ls = sh + 1024;                // G01 row 4096
    if (tid < 128)
      reinterpret_cast<float4*>(lu)[tid] = reinterpret_cast<const float4*>(f0 + i * 512)[tid];
    else
      reinterpret_cast<float4*>(lv)[tid - 128] = reinterpret_cast<const float4*>(f1 + j * 512)[tid - 128];
    __syncthreads();
#pragma unroll
    for (int r = 0; r < 16; ++r) {
      int idx = r * 256 + tid;
      int uv = idx >> 6, pq = idx & 63;
      int a = uv >> 3, c = uv & 7, p = pq >> 3, q = pq & 7;
      float acc = 0.f;
#pragma unroll
      for (int b = 0; b < 8; ++b)
        acc = fmaf(lu[a * 64 + b * 8 + p], lv[b * 64 + c * 8 + q], acc);
      ls[idx] = acc;
    }
    __syncthreads();
    short8v* dst = reinterpret_cast<short8v*>(G01p);
#pragma unroll
    for (int it = 0; it < 2; ++it) {
      int item = it * 256 + tid;          // ks(2)*mf(4)*l(64)
      int ks = item >> 8, mf = (item >> 6) & 3, l = item & 63;
      short8v hi, lo;
#pragma unroll
      for (int j2 = 0; j2 < 8; ++j2) {
        float v = ls[(mf * 16 + (l & 15)) * 64 + ks * 32 + 8 * (l >> 4) + j2];
        unsigned short h = f2bf(v);
        hi[j2] = (short)h; lo[j2] = (short)f2bf(v - bf2f(h));
      }
      size_t base = ((((size_t)ij * 2 + ks) * 4 + mf) * 2) * 64 + l;
      dst[base] = hi; dst[base + 64] = lo;
    }
  } else if (bb < 128) {                  // CP: B-frag, st = bb-64
    int st = bb - 64;
    float* ls = sh;
#pragma unroll
    for (int r = 0; r < 4; ++r) {
      int f4 = r * 256 + tid;             // pq = f4>>4, o4 = f4&15
      reinterpret_cast<float4*>(ls)[f4] =
          reinterpret_cast<const float4*>(core)[(f4 >> 4) * 1024 + st * 16 + (f4 & 15)];
    }
    __syncthreads();
    short8v* dst = reinterpret_cast<short8v*>(CP);
#pragma unroll
    for (int it = 0; it < 2; ++it) {
      int item = it * 256 + tid;          // ks(2)*nf(4)*l(64)
      int ks = item >> 8, nf = (item >> 6) & 3, l = item & 63;
      short8v hi, lo;
#pragma unroll
      for (int j2 = 0; j2 < 8; ++j2) {
        float v = ls[(ks * 32 + 8 * (l >> 4) + j2) * 64 + nf * 16 + (l & 15)];
        unsigned short h = f2bf(v);
        hi[j2] = (short)h; lo[j2] = (short)f2bf(v - bf2f(h));
      }
      size_t base = ((((size_t)st * 2 + ks) * 4 + nf) * 2) * 64 + l;
      dst[base] = hi; dst[base + 64] = lo;
    }
  } else if (bb < 256) {                  // G23p: A-frag, ks = bb-128 (compute G23 inline)
    int ks = bb - 128;                    // k2 = st*64+ac ; st = ks>>1, ac = (ks&1)*32+acr
    int st = ks >> 1, acb = (ks & 1) * 32;
    int s = st >> 3, t = st & 7;
    float* lu = sh;                       // f2 full 4096
    float* lv = sh + 4096;                // f3 full 4096
    float* ls = sh + 8192;                // [kl][acr] 2048
#pragma unroll
    for (int r = 0; r < 4; ++r) {
      reinterpret_cast<float4*>(lu)[r * 256 + tid] = reinterpret_cast<const float4*>(f2)[r * 256 + tid];
      reinterpret_cast<float4*>(lv)[r * 256 + tid] = reinterpret_cast<const float4*>(f3)[r * 256 + tid];
    }
    __syncthreads();
#pragma unroll
    for (int r = 0; r < 8; ++r) {
      int idx = r * 256 + tid;            // kl = idx>>5, acr = idx&31
      int kl = idx >> 5, ac = acb + (idx & 31);
      int a = ac >> 3, c = ac & 7, k = kl >> 3, l2 = kl & 7;
      float acc = 0.f;
#pragma unroll
      for (int d = 0; d < 8; ++d)
        acc = fmaf(lu[k * 512 + c * 64 + d * 8 + s], lv[l2 * 512 + d * 64 + a * 8 + t], acc);
      ls[idx] = acc;
    }
    __syncthreads();
    short8v* dst = reinterpret_cast<short8v*>(G23p);
    int mf = tid >> 6, l = tid & 63;
    short8v hi, lo;
#pragma unroll
    for (int j2 = 0; j2 < 8; ++j2) {
      float v = ls[(mf * 16 + (l & 15)) * 32 + 8 * (l >> 4) + j2];
      unsigned short h = f2bf(v);
      hi[j2] = (short)h; lo[j2] = (short)f2bf(v - bf2f(h));
    }
    size_t base = (((size_t)ks * 4 + mf) * 2) * 64 + l;
    dst[base] = hi; dst[base + 64] = lo;
  } else {                                // OFp: 8 blocks, f-group g = bb-256
    int g = bb - 256;
    float* ls = sh;
#pragma unroll
    for (int it = 0; it < 8; ++it) {
      int f4 = it * 256 + tid;            // o = f4>>5, c4 = f4&31
      reinterpret_cast<float4*>(ls)[f4] =
          reinterpret_cast<const float4*>(OF_)[(f4 >> 5) * 256 + g * 32 + (f4 & 31)];
    }
    __syncthreads();
    short8v* dst = reinterpret_cast<short8v*>(OFp);
#pragma unroll
    for (int it = 0; it < 4; ++it) {
      int item = it * 256 + tid;          // nfl(8)*ks(2)*l(64)
      int nfl = item >> 7, ks = (item >> 6) & 1, l = item & 63;
      short8v hi, lo;
#pragma unroll
      for (int j2 = 0; j2 < 8; ++j2) {
        float v = ls[(ks * 32 + 8 * (l >> 4) + j2) * 128 + nfl * 16 + (l & 15)];
        unsigned short h = f2bf(v);
        hi[j2] = (short)h; lo[j2] = (short)f2bf(v - bf2f(h));
      }
      int nfg = g * 8 + nfl;
      size_t base = (((size_t)nfg * 2 + ks) * 2) * 64 + l;
      dst[base] = hi; dst[base + 64] = lo;
    }
  }
}

// ---------------- fused T4 build (validated v6) ----------------

__global__ __launch_bounds__(256) void k_t4f(const unsigned short* __restrict__ G01p,
                                             const unsigned short* __restrict__ CP,
                                             const unsigned short* __restrict__ G23p,
                                             float* __restrict__ T4part) {
  int bid = blockIdx.x;
  int ij = bid >> 3, stc = bid & 7;
  int tid = threadIdx.x;
  int w = tid >> 6, l = tid & 63;
  const short8v* gp = reinterpret_cast<const short8v*>(G01p);
  const short8v* cp = reinterpret_cast<const short8v*>(CP);
  const short8v* ga = reinterpret_cast<const short8v*>(G23p);
  short8v a0h = gp[((((size_t)ij * 2 + 0) * 4 + w) * 2) * 64 + l];
  short8v a0l = gp[((((size_t)ij * 2 + 0) * 4 + w) * 2) * 64 + 64 + l];
  short8v a1h = gp[((((size_t)ij * 2 + 1) * 4 + w) * 2) * 64 + l];
  short8v a1l = gp[((((size_t)ij * 2 + 1) * 4 + w) * 2) * 64 + 64 + l];
  __shared__ float Ef[64 * 66];
  __shared__ short EB[8192];
  short8v* EBv = reinterpret_cast<short8v*>(EB);
  f32x4 accT[4];
#pragma unroll
  for (int nf = 0; nf < 4; ++nf) accT[nf] = (f32x4){0.f, 0.f, 0.f, 0.f};

#pragma unroll 1
  for (int si = 0; si < 8; ++si) {
    int st = stc * 8 + si;
    f32x4 accE[4];
#pragma unroll
    for (int nf = 0; nf < 4; ++nf) accE[nf] = (f32x4){0.f, 0.f, 0.f, 0.f};
#pragma unroll
    for (int nf = 0; nf < 4; ++nf) {
      short8v bh0 = cp[((((size_t)st * 2 + 0) * 4 + nf) * 2) * 64 + l];
      short8v bl0 = cp[((((size_t)st * 2 + 0) * 4 + nf) * 2) * 64 + 64 + l];
      short8v bh1 = cp[((((size_t)st * 2 + 1) * 4 + nf) * 2) * 64 + l];
      short8v bl1 = cp[((((size_t)st * 2 + 1) * 4 + nf) * 2) * 64 + 64 + l];
      accE[nf] = __builtin_amdgcn_mfma_f32_16x16x32_bf16(a0h, bh0, accE[nf], 0, 0, 0);
      accE[nf] = __builtin_amdgcn_mfma_f32_16x16x32_bf16(a0l, bh0, accE[nf], 0, 0, 0);
      accE[nf] = __builtin_amdgcn_mfma_f32_16x16x32_bf16(a0h, bl0, accE[nf], 0, 0, 0);
      accE[nf] = __builtin_amdgcn_mfma_f32_16x16x32_bf16(a1h, bh1, accE[nf], 0, 0, 0);
      accE[nf] = __builtin_amdgcn_mfma_f32_16x16x32_bf16(a1l, bh1, accE[nf], 0, 0, 0);
      accE[nf] = __builtin_amdgcn_mfma_f32_16x16x32_bf16(a1h, bl1, accE[nf], 0, 0, 0);
    }
#pragma unroll
    for (int nf = 0; nf < 4; ++nf)
#pragma unroll
      for (int r = 0; r < 4; ++r)
        Ef[(w * 16 + 4 * (l >> 4) + r) * 66 + nf * 16 + (l & 15)] = accE[nf][r];
    __syncthreads();
#pragma unroll
    for (int it = 0; it < 2; ++it) {
      int item = it * 256 + tid;
      int kch = item >> 8, nf = (item >> 6) & 3, l2 = item & 63;
      short8v hi, lo;
#pragma unroll
      for (int j = 0; j < 8; ++j) {
        float v = Ef[(kch * 32 + 8 * (l2 >> 4) + j) * 66 + nf * 16 + (l2 & 15)];
        unsigned short hh = f2bf(v);
        hi[j] = (short)hh; lo[j] = (short)f2bf(v - bf2f(hh));
      }
      EBv[((kch * 4 + nf) * 2 + 0) * 64 + l2] = hi;
      EBv[((kch * 4 + nf) * 2 + 1) * 64 + l2] = lo;
    }
    __syncthreads();
#pragma unroll
    for (int kch = 0; kch < 2; ++kch) {
      size_t abase = ((((size_t)(st * 2 + kch)) * 4 + w) * 2) * 64 + l;
      short8v ah = ga[abase], al = ga[abase + 64];
#pragma unroll
      for (int nf = 0; nf < 4; ++nf) {
        short8v bh = EBv[((kch * 4 + nf) * 2 + 0) * 64 + l];
        short8v bl = EBv[((kch * 4 + nf) * 2 + 1) * 64 + l];
        accT[nf] = __builtin_amdgcn_mfma_f32_16x16x32_bf16(ah, bh, accT[nf], 0, 0, 0);
        accT[nf] = __builtin_amdgcn_mfma_f32_16x16x32_bf16(al, bh, accT[nf], 0, 0, 0);
        accT[nf] = __builtin_amdgcn_mfma_f32_16x16x32_bf16(ah, bl, accT[nf], 0, 0, 0);
      }
    }
  }
#pragma unroll
  for (int nf = 0; nf < 4; ++nf)
#pragma unroll
    for (int r = 0; r < 4; ++r) {
      int row = w * 16 + 4 * (l >> 4) + r;
      T4part[(((size_t)stc * 64 + ij) * 64 + row) * 64 + nf * 16 + (l & 15)] = accT[nf][r];
    }
}

// ---------------- reduce T4 partials + pack x-GEMM B-frag ----------------

__global__ __launch_bounds__(256) void k_pack2(const float* __restrict__ T4part,
                                               unsigned short* __restrict__ Bp) {
  int kb = blockIdx.x, tid = threadIdx.x;
  __shared__ float ls[2048];
  f32x4 a0 = {0.f, 0.f, 0.f, 0.f}, a1 = a0;
#pragma unroll
  for (int kc = 0; kc < 8; ++kc) {
    const f32x4* src = reinterpret_cast<const f32x4*>(T4part + (size_t)kc * 262144 + kb * 2048);
    a0 += src[tid];
    a1 += src[256 + tid];
  }
  reinterpret_cast<f32x4*>(ls)[tid] = a0;
  reinterpret_cast<f32x4*>(ls)[256 + tid] = a1;
  __syncthreads();
  short8v* dst = reinterpret_cast<short8v*>(Bp);
  int nf = tid >> 6, l = tid & 63;
  short8v hi, lo;
#pragma unroll
  for (int j = 0; j < 8; ++j) {
    float v = ls[(8 * (l >> 4) + j) * 64 + nf * 16 + (l & 15)];
    unsigned short h = f2bf(v);
    hi[j] = (short)h; lo[j] = (short)f2bf(v - bf2f(h));
  }
  size_t base = (size_t)kb * 512 + (nf * 2) * 64 + l;
  dst[base] = hi; dst[base + 64] = lo;
}

// ---------------- Y = x @ T4 (split-K x16, x prefetch) ----------------

__global__ __launch_bounds__(256) void k_ymm(const float* __restrict__ x,
                                             const unsigned short* __restrict__ Bp,
                                             float* __restrict__ Ypart) {
  int mt = blockIdx.x >> 4, kc = blockIdx.x & 15;
  int w = threadIdx.x >> 6, l = threadIdx.x & 63;
  int kg = l >> 4, lm = l & 15;
  const float4* xp = reinterpret_cast<const float4*>(
      x + (size_t)(mt * 64 + w * 16 + lm) * 4096 + kc * 256 + kg * 8);
  f32x4 acc0 = {0.f, 0.f, 0.f, 0.f}, acc1 = acc0, acc2 = acc0, acc3 = acc0;
  float4 xa = xp[0], xb = xp[1];
#pragma unroll 1
  for (int s = 0; s < 8; ++s) {
    int sn = (s < 7) ? s + 1 : 7;         // clamped prefetch
    float4 na = xp[sn * 8], nb = xp[sn * 8 + 1];
    float xs[8] = {xa.x, xa.y, xa.z, xa.w, xb.x, xb.y, xb.z, xb.w};
    short8v ah, al;
#pragma unroll
    for (int j = 0; j < 8; ++j) {         // trunc split
      unsigned u = __builtin_bit_cast(unsigned, xs[j]);
      unsigned short h = (unsigned short)(u >> 16);
      ah[j] = (short)h;
      float lo = xs[j] - bf2f(h);
      al[j] = (short)(__builtin_bit_cast(unsigned, lo) >> 16);
    }
    const short8v* bp = reinterpret_cast<const short8v*>(Bp + (size_t)(kc * 8 + s) * 4096) + l;
    short8v bh0 = bp[0],   bl0 = bp[64];
    short8v bh1 = bp[128], bl1 = bp[192];
    short8v bh2 = bp[256], bl2 = bp[320];
    short8v bh3 = bp[384], bl3 = bp[448];
    acc0 = __builtin_amdgcn_mfma_f32_16x16x32_bf16(ah, bh0, acc0, 0, 0, 0);
    acc1 = __builtin_amdgcn_mfma_f32_16x16x32_bf16(ah, bh1, acc1, 0, 0, 0);
    acc2 = __builtin_amdgcn_mfma_f32_16x16x32_bf16(ah, bh2, acc2, 0, 0, 0);
    acc3 = __builtin_amdgcn_mfma_f32_16x16x32_bf16(ah, bh3, acc3, 0, 0, 0);
    acc0 = __builtin_amdgcn_mfma_f32_16x16x32_bf16(al, bh0, acc0, 0, 0, 0);
    acc1 = __builtin_amdgcn_mfma_f32_16x16x32_bf16(al, bh1, acc1, 0, 0, 0);
    acc2 = __builtin_amdgcn_mfma_f32_16x16x32_bf16(al, bh2, acc2, 0, 0, 0);
    acc3 = __builtin_amdgcn_mfma_f32_16x16x32_bf16(al, bh3, acc3, 0, 0, 0);
    acc0 = __builtin_amdgcn_mfma_f32_16x16x32_bf16(ah, bl0, acc0, 0, 0, 0);
    acc1 = __builtin_amdgcn_mfma_f32_16x16x32_bf16(ah, bl1, acc1, 0, 0, 0);
    acc2 = __builtin_amdgcn_mfma_f32_16x16x32_bf16(ah, bl2, acc2, 0, 0, 0);
    acc3 = __builtin_amdgcn_mfma_f32_16x16x32_bf16(ah, bl3, acc3, 0, 0, 0);
    xa = na; xb = nb;
  }
  float* yb = Ypart + (size_t)kc * 262144 + (size_t)(mt * 64 + w * 16) * 64;
#pragma unroll
  for (int r = 0; r < 4; ++r) {
    yb[(kg * 4 + r) * 64 + 0  + lm] = acc0[r];
    yb[(kg * 4 + r) * 64 + 16 + lm] = acc1[r];
    yb[(kg * 4 + r) * 64 + 32 + lm] = acc2[r];
    yb[(kg * 4 + r) * 64 + 48 + lm] = acc3[r];
  }
}

// ---------------- fused: reduce Ypart + out = Y @ OF + bias ----------------

__global__ __launch_bounds__(256) void k_out4(const float* __restrict__ Ypart,
                                              const unsigned short* __restrict__ OFp,
                                              const float* __restrict__ bias,
                                              float* __restrict__ out) {
  int mt16 = blockIdx.x;
  int tid = threadIdx.x;
  __shared__ float ls[1024];
  {
    f32x4 a = {0.f, 0.f, 0.f, 0.f};
#pragma unroll
    for (int kc = 0; kc < 16; ++kc)
      a += *reinterpret_cast<const f32x4*>(Ypart + (size_t)kc * 262144 + (size_t)mt16 * 1024 + tid * 4);
    *reinterpret_cast<f32x4*>(ls + tid * 4) = a;
  }
  __syncthreads();
  int w = tid >> 6, l = tid & 63;
  short8v ya0, yl0, ya1, yl1;
#pragma unroll
  for (int j = 0; j < 8; ++j) {
    float v0 = ls[(l & 15) * 64 + 0  + 8 * (l >> 4) + j];
    float v1 = ls[(l & 15) * 64 + 32 + 8 * (l >> 4) + j];
    unsigned short h0 = (unsigned short)(__builtin_bit_cast(unsigned, v0) >> 16);
    unsigned short h1 = (unsigned short)(__builtin_bit_cast(unsigned, v1) >> 16);
    ya0[j] = (short)h0; yl0[j] = (short)(__builtin_bit_cast(unsigned, v0 - bf2f(h0)) >> 16);
    ya1[j] = (short)h1; yl1[j] = (short)(__builtin_bit_cast(unsigned, v1 - bf2f(h1)) >> 16);
  }
  const short8v* op = reinterpret_cast<const short8v*>(OFp);
#pragma unroll 4
  for (int nf = 0; nf < 16; ++nf) {
    int nfg = w * 16 + nf;
    size_t bb = (((size_t)nfg * 2) * 2) * 64 + l;
    short8v bh0 = op[bb], bl0 = op[bb + 64], bh1 = op[bb + 128], bl1 = op[bb + 192];
    f32x4 acc = {0.f, 0.f, 0.f, 0.f};
    acc = __builtin_amdgcn_mfma_f32_16x16x32_bf16(ya0, bh0, acc, 0, 0, 0);
    acc = __builtin_amdgcn_mfma_f32_16x16x32_bf16(yl0, bh0, acc, 0, 0, 0);
    acc = __builtin_amdgcn_mfma_f32_16x16x32_bf16(ya0, bl0, acc, 0, 0, 0);
    acc = __builtin_amdgcn_mfma_f32_16x16x32_bf16(ya1, bh1, acc, 0, 0, 0);
    acc = __builtin_amdgcn_mfma_f32_16x16x32_bf16(yl1, bh1, acc, 0, 0, 0);
    acc = __builtin_amdgcn_mfma_f32_16x16x32_bf16(ya1, bl1, acc, 0, 0, 0);
    float bv = bias[nfg * 16 + (l & 15)];
#pragma unroll
    for (int r = 0; r < 4; ++r)
      out[(size_t)(mt16 * 16 + 4 * (l >> 4) + r) * 1024 + nfg * 16 + (l & 15)] = acc[r] + bv;
  }
}

// ---------------- fallback (round-1 verified path) ----------------

__global__ __launch_bounds__(256) void k_build(const float* __restrict__ f0,
                                               const float* __restrict__ f1,
                                               const float* __restrict__ f2,
                                               const float* __restrict__ f3,
                                               float* __restrict__ G01,
                                               float* __restrict__ G23) {
  int bb = blockIdx.x, tid = threadIdx.x;
  __shared__ float lu[512], lv[512];
  bool is01 = bb < 64;
  int pairi = is01 ? bb : bb - 64;
  int iA = pairi >> 3, iB = pairi & 7;
  const float* fu = is01 ? f0 : f2;
  const float* fv = is01 ? f1 : f3;
  if (tid < 128)
    reinterpret_cast<float4*>(lu)[tid] = reinterpret_cast<const float4*>(fu + iA * 512)[tid];
  else
    reinterpret_cast<float4*>(lv)[tid - 128] = reinterpret_cast<const float4*>(fv + iB * 512)[tid - 128];
  __syncthreads();
  float* dst = is01 ? G01 : G23;
#pragma unroll
  for (int r = 0; r < 16; ++r) {
    int idx = r * 256 + tid;
    int uv = idx >> 6, pq = idx & 63;
    int a = uv >> 3, c = uv & 7, p = pq >> 3, q = pq & 7;
    float acc = 0.f;
    if (is01) {
#pragma unroll
      for (int b = 0; b < 8; ++b)
        acc = fmaf(lu[a * 64 + b * 8 + p], lv[b * 64 + c * 8 + q], acc);
    } else {
#pragma unroll
      for (int d = 0; d < 8; ++d)
        acc = fmaf(lu[c * 64 + d * 8 + p], lv[d * 64 + a * 8 + q], acc);
    }
    dst[pairi * 4096 + idx] = acc;
  }
}

__global__ __launch_bounds__(256) void k_t4(const float* __restrict__ A,
                                            const float* __restrict__ B,
                                            const float* __restrict__ core,
                                            float* __restrict__ T4) {
  int bid = blockIdx.x;
  int ij = bid >> 4, kl0 = (bid & 15) * 4;
  __shared__ float lA[4096];
  __shared__ float lS[4][4096];
  int tid = threadIdx.x;
#pragma unroll
  for (int r = 0; r < 4; ++r)
    reinterpret_cast<float4*>(lA)[r * 256 + tid] =
        reinterpret_cast<const float4*>(A + ij * 4096)[r * 256 + tid];
  __syncthreads();
  int pq0 = (tid >> 4) << 2;
  int st04 = tid & 15;
#pragma unroll 1
  for (int m = 0; m < 4; ++m) {
    const float4* Bp = reinterpret_cast<const float4*>(B + (kl0 + m) * 4096);
    float acc[4][4] = {{0.f}};
    for (int ac = 0; ac < 64; ++ac) {
      float4 av = reinterpret_cast<float4*>(lA)[ac * 16 + (pq0 >> 2)];
      float4 bv = Bp[ac * 16 + st04];
      float au[4] = {av.x, av.y, av.z, av.w};
      float bu[4] = {bv.x, bv.y, bv.z, bv.w};
#pragma unroll
      for (int u = 0; u < 4; ++u)
#pragma unroll
        for (int v = 0; v < 4; ++v)
          acc[u][v] = fmaf(au[u], bu[v], acc[u][v]);
    }
    float4* S4 = reinterpret_cast<float4*>(lS[m]);
#pragma unroll
    for (int u = 0; u < 4; ++u)
      S4[(pq0 + u) * 16 + st04] = make_float4(acc[u][0], acc[u][1], acc[u][2], acc[u][3]);
  }
  __syncthreads();
  int o44 = tid & 15, seg = tid >> 4;
  const float4* c4 = reinterpret_cast<const float4*>(core);
  float4 r0 = {0, 0, 0, 0}, r1 = r0, r2 = r0, r3 = r0;
  for (int n = 0; n < 256; ++n) {
    int midx = seg * 256 + n;
    float4 cv = c4[midx * 16 + o44];
    float s0 = lS[0][midx], s1 = lS[1][midx], s2 = lS[2][midx], s3 = lS[3][midx];
    r0.x = fmaf(s0, cv.x, r0.x); r0.y = fmaf(s0, cv.y, r0.y);
    r0.z = fmaf(s0, cv.z, r0.z); r0.w = fmaf(s0, cv.w, r0.w);
    r1.x = fmaf(s1, cv.x, r1.x); r1.y = fmaf(s1, cv.y, r1.y);
    r1.z = fmaf(s1, cv.z, r1.z); r1.w = fmaf(s1, cv.w, r1.w);
    r2.x = fmaf(s2, cv.x, r2.x); r2.y = fmaf(s2, cv.y, r2.y);
    r2.z = fmaf(s2, cv.z, r2.z); r2.w = fmaf(s2, cv.w, r2.w);
    r3.x = fmaf(s3, cv.x, r3.x); r3.y = fmaf(s3, cv.y, r3.y);
    r3.z = fmaf(s3, cv.z, r3.z); r3.w = fmaf(s3, cv.w, r3.w);
  }
  float4* red = reinterpret_cast<float4*>(lA);
  red[(seg * 4 + 0) * 16 + o44] = r0;
  red[(seg * 4 + 1) * 16 + o44] = r1;
  red[(seg * 4 + 2) * 16 + o44] = r2;
  red[(seg * 4 + 3) * 16 + o44] = r3;
  __syncthreads();
  int m2 = tid >> 6, o = tid & 63;
  float t = 0.f;
#pragma unroll
  for (int s2 = 0; s2 < 16; ++s2) t += lA[(s2 * 4 + m2) * 64 + o];
  T4[(ij * 64 + kl0 + m2) * 64 + o] = t;
}

__global__ __launch_bounds__(256) void k_y(const float* __restrict__ x,
                                           const float* __restrict__ T4,
                                           float* __restrict__ Y) {
  int b0 = blockIdx.x * 16;
  __shared__ float lx[1024];
  int tid = threadIdx.x;
  int o = tid & 63, rg = tid >> 6;
  float acc0 = 0.f, acc1 = 0.f, acc2 = 0.f, acc3 = 0.f;
  const float4* lx4 = reinterpret_cast<const float4*>(lx);
  for (int kc = 0; kc < 4096; kc += 64) {
    __syncthreads();
    reinterpret_cast<float4*>(lx)[tid] =
        *reinterpret_cast<const float4*>(x + (b0 + (tid >> 4)) * 4096 + kc + (tid & 15) * 4);
    __syncthreads();
#pragma unroll 4
    for (int kk = 0; kk < 64; kk += 4) {
      float c0 = T4[(kc + kk + 0) * 64 + o];
      float c1 = T4[(kc + kk + 1) * 64 + o];
      float c2 = T4[(kc + kk + 2) * 64 + o];
      float c3 = T4[(kc + kk + 3) * 64 + o];
      float4 xv;
      xv = lx4[(rg * 4 + 0) * 16 + (kk >> 2)];
      acc0 = fmaf(xv.x, c0, fmaf(xv.y, c1, fmaf(xv.z, c2, fmaf(xv.w, c3, acc0))));
      xv = lx4[(rg * 4 + 1) * 16 + (kk >> 2)];
      acc1 = fmaf(xv.x, c0, fmaf(xv.y, c1, fmaf(xv.z, c2, fmaf(xv.w, c3, acc1))));
      xv = lx4[(rg * 4 + 2) * 16 + (kk >> 2)];
      acc2 = fmaf(xv.x, c0, fmaf(xv.y, c1, fmaf(xv.z, c2, fmaf(xv.w, c3, acc2))));
      xv = lx4[(rg * 4 + 3) * 16 + (kk >> 2)];
      acc3 = fmaf(xv.x, c0, fmaf(xv.y, c1, fmaf(xv.z, c2, fmaf(xv.w, c3, acc3))));
    }
  }
  Y[(b0 + rg * 4 + 0) * 64 + o] = acc0;
  Y[(b0 + rg * 4 + 1) * 64 + o] = acc1;
  Y[(b0 + rg * 4 + 2) * 64 + o] = acc2;
  Y[(b0 + rg * 4 + 3) * 64 + o] = acc3;
}

__global__ __launch_bounds__(256) void k_out(const float* __restrict__ Y,
                                             const float* __restrict__ OF_,
                                             const float* __restrict__ bias,
                                             float* __restrict__ out) {
  int b0 = blockIdx.x * 16;
  int tid = threadIdx.x;
  __shared__ float lY[1024];
  reinterpret_cast<float4*>(lY)[tid] =
      *reinterpret_cast<const float4*>(Y + (b0 + (tid >> 4)) * 64 + (tid & 15) * 4);
  __syncthreads();
  float4 acc[16];
#pragma unroll
  for (int r = 0; r < 16; ++r) acc[r] = make_float4(0.f, 0.f, 0.f, 0.f);
  for (int oo = 0; oo < 64; ++oo) {
    float4 w = *reinterpret_cast<const float4*>(OF_ + oo * 1024 + tid * 4);
#pragma unroll
    for (int r = 0; r < 16; ++r) {
      float yv = lY[r * 64 + oo];
      acc[r].x = fmaf(yv, w.x, acc[r].x);
      acc[r].y = fmaf(yv, w.y, acc[r].y);
      acc[r].z = fmaf(yv, w.z, acc[r].z);
      acc[r].w = fmaf(yv, w.w, acc[r].w);
    }
  }
  float4 bv = *reinterpret_cast<const float4*>(bias + tid * 4);
#pragma unroll
  for (int r = 0; r < 16; ++r) {
    float4 v = acc[r];
    v.x += bv.x; v.y += bv.y; v.z += bv.z; v.w += bv.w;
    *reinterpret_cast<float4*>(out + (b0 + r) * 1024 + tid * 4) = v;
  }
}

// ---------------- host ----------------

extern "C" void kernel_launch(void* const* d_in, const int* in_sizes, int n_in,
                              void* d_out, int out_size, void* d_ws, size_t ws_size,
                              hipStream_t stream) {
  const float* x    = (const float*)d_in[0];
  const float* f0   = (const float*)d_in[1];
  const float* f1   = (const float*)d_in[2];
  const float* f2   = (const float*)d_in[3];
  const float* f3   = (const float*)d_in[4];
  const float* core = (const float*)d_in[5];
  const float* ofac = (const float*)d_in[6];
  const float* bias = (const float*)d_in[7];
  float* out = (float*)d_out;
  float* ws = (float*)d_ws;

  if (ws_size >= WS_NEED) {
    unsigned short* G01p = (unsigned short*)(ws + 524288);
    unsigned short* CP   = (unsigned short*)(ws + 786432);
    unsigned short* G23p = (unsigned short*)(ws + 1048576);
    unsigned short* Bp   = (unsigned short*)(ws + 1310720);
    unsigned short* OFp  = (unsigned short*)(ws + 1572864);
    float* T4part = ws + 1638400;         // 8 x 262144
    float* Ypart  = ws + 3735552;         // 16 x 262144

    k_packs<<<264, 256, 0, stream>>>(f0, f1, f2, f3, core, ofac, G01p, CP, G23p, OFp);
    k_t4f<<<512, 256, 0, stream>>>(G01p, CP, G23p, T4part);
    k_pack2<<<128, 256, 0, stream>>>(T4part, Bp);
    k_ymm<<<1024, 256, 0, stream>>>(x, Bp, Ypart);
    k_out4<<<256, 256, 0, stream>>>(Ypart, OFp, bias, out);
  } else {
    float* G01 = ws;
    float* G23 = ws + 262144;
    float* T4 = ws + 524288;
    float* Yb = ws + 786432;
    k_build<<<128, 256, 0, stream>>>(f0, f1, f2, f3, G01, G23);
    k_t4<<<1024, 256, 0, stream>>>(G01, G23, core, T4);
    k_y<<<256, 256, 0, stream>>>(x, T4, Yb);
    k_out<<<256, 256, 0, stream>>>(Yb, ofac, bias, out);
  }
}